// Round 8
// baseline (1209.433 us; speedup 1.0000x reference)
//
#include <hip/hip_runtime.h>
#include <hip/hip_bf16.h>
#include <math.h>
#include <cstddef>

// Problem constants
#define BATCH 4
#define WDIM 256
#define CDIM 128
#define WS 4
#define SHIFT 3
#define HEADS 4
#define HD 32
#define NTOK 16

typedef __attribute__((ext_vector_type(8))) short short8;
typedef __attribute__((ext_vector_type(4))) int int4v;
typedef __attribute__((ext_vector_type(4))) float f32x4;

__device__ __forceinline__ int regionOf(int v) {
    return v < (WDIM - WS) ? 0 : (v < (WDIM - SHIFT) ? 1 : 2);
}

__device__ __forceinline__ short f2bf(float v) {
    __hip_bfloat16 h = __float2bfloat16(v);
    return __builtin_bit_cast(short, h);
}
__device__ __forceinline__ float bf2f(short s) {
    unsigned u = ((unsigned)(unsigned short)s) << 16;
    return __builtin_bit_cast(float, u);
}

// ---------------------------------------------------------------------------
// Repack attention weights: [c][j] fp32 -> [j][c] bf16 (MFMA A-operand order)
// ---------------------------------------------------------------------------
__global__ __launch_bounds__(256) void repack_attnw(
    const float* __restrict__ qkv_w,   // (128, 384)
    const float* __restrict__ proj_w,  // (128, 128)
    __hip_bfloat16* __restrict__ qkvw_rep,   // (384, 128)
    __hip_bfloat16* __restrict__ projw_rep)  // (128, 128)
{
    int idx = blockIdx.x * 256 + threadIdx.x;   // < 65536
    if (idx < 49152) {
        int j = idx >> 7, c = idx & 127;
        qkvw_rep[idx] = __float2bfloat16(qkv_w[c * 384 + j]);
    } else {
        int k = idx - 49152;
        int j = k >> 7, c = k & 127;
        projw_rep[k] = __float2bfloat16(proj_w[c * 128 + j]);
    }
}

// ---------------------------------------------------------------------------
// Kernel A: fused upsample + shifted-window MSA + residual, MFMA version.
// (unchanged — R4 structure: col-major xrow, operand-swapped softmax)
// ---------------------------------------------------------------------------
#define XROW_RS 2114   // row stride in floats; 2114 mod 32 = 2 (bank spread)

__global__ __launch_bounds__(256, 4) void attn_kernel(
    const float* __restrict__ xin,
    const __hip_bfloat16* __restrict__ qkvw_rep,
    const __hip_bfloat16* __restrict__ projw_rep,
    const float* __restrict__ qkv_b,
    const float* __restrict__ proj_b,
    const float* __restrict__ rpb,
    __hip_bfloat16* __restrict__ xatt)
{
    __shared__ __align__(16) char smem[40864];
    float* xrowF  = (float*)smem;                      // col-major [2][64][33(n)]
    short* qkvs   = (short*)smem;                      // [32][264]
    short* aoutS  = (short*)smem;                      // [32][136]
    short* Xb     = (short*)(smem + 16912);            // [32][136]
    short* Ps     = (short*)(smem + 25616);            // [128][16]
    short* Vt     = (short*)(smem + 29712);            // [256][16]
    float* rpbs   = (float*)(smem + 37904);
    float* qkvbS  = (float*)(smem + 38688);
    float* projbS = (float*)(smem + 40224);
    float* tokw2  = (float*)(smem + 40736);

    const int tid = threadIdx.x;
    const int bid = blockIdx.x;
    const int l   = tid & 63;
    const int wv  = tid >> 6;
    const int lm  = l & 15;
    const int lq  = l >> 4;

    if (tid < 196) rpbs[tid] = rpb[tid];
    for (int i = tid; i < 384; i += 256) qkvbS[i] = qkv_b[i];
    if (tid < 128) projbS[tid] = proj_b[tid];

    // ---- Stage 1: load raw rows (2 per token), scatter column-major -----
    #pragma unroll
    for (int k = 0; k < 4; k++) {
        int id = tid + k * 256;
        int n   = id >> 5;
        int row = (id >> 4) & 1;
        int ll  = id & 15;
        int w_  = n >> 4, nn = n & 15;
        int win = bid * 2 + w_;
        int b   = win >> 12;
        int wh  = (win >> 6) & 63;
        int ww  = win & 63;
        int r = nn >> 2, c = nn & 3;
        int gh = (wh * 4 + r + SHIFT) & 255;
        int gw = (ww * 4 + c + SHIFT) & 255;
        float pos2 = gw * (127.0f / 255.0f);
        int lo2 = (int)floorf(pos2);
        int hi2 = min(lo2 + 1, 127);
        if (row == 0 && ll == 0) tokw2[n] = pos2 - (float)lo2;
        int src = row == 0 ? lo2 : hi2;
        const float4* rp = (const float4*)(xin + (((size_t)b * 256 + gh) * 128 + src) * 64);
        float4 v = rp[ll];
        float* bp = xrowF + row * XROW_RS + n + (4 * ll) * 33;
        bp[0]      = v.x;
        bp[33]     = v.y;
        bp[66]     = v.z;
        bp[99]     = v.w;
    }
    __syncthreads();

    // ---- Stage 2: interp along last axis -> Xb bf16 ---------------------
    {
        int n = tid >> 3;
        int jj = tid & 7;
        float w2 = tokw2[n];
        const float* x0 = xrowF + n;
        const float* x1 = x0 + XROW_RS;
        #pragma unroll
        for (int p = 0; p < 8; p++) {
            unsigned pk = 0;
            #pragma unroll
            for (int q = 0; q < 2; q++) {
                int cc = jj * 16 + p * 2 + q;
                float pos3 = cc * (63.0f / 127.0f);
                int lo3 = (int)floorf(pos3);
                float w3 = pos3 - (float)lo3;
                int o = lo3 * 33;
                float v0 = x0[o] * (1.f - w3) + x0[o + 33] * w3;
                float v1 = x1[o] * (1.f - w3) + x1[o + 33] * w3;
                float out = v0 * (1.f - w2) + v1 * w2;
                pk |= ((unsigned)(unsigned short)f2bf(out)) << (16 * q);
            }
            *(unsigned*)&Xb[n * 136 + jj * 16 + p * 2] = pk;
        }
    }
    __syncthreads();

    // ---- Stage 3: QKV GEMM (M=384 j, N=32 tok, K=128) -------------------
    {
        f32x4 qacc[6][2];
        #pragma unroll
        for (int a = 0; a < 6; a++)
            #pragma unroll
            for (int t = 0; t < 2; t++) qacc[a][t] = (f32x4)0.0f;

        for (int ks = 0; ks < 4; ks++) {
            short8 af[6];
            #pragma unroll
            for (int jj = 0; jj < 6; jj++) {
                const int4v* gp = (const int4v*)(qkvw_rep +
                    (size_t)(wv * 96 + jj * 16 + lm) * 128 + ks * 32 + lq * 8);
                af[jj] = __builtin_bit_cast(short8, *gp);
            }
            short8 bfr[2];
            #pragma unroll
            for (int tt = 0; tt < 2; tt++)
                bfr[tt] = *(const short8*)&Xb[(tt * 16 + lm) * 136 + ks * 32 + lq * 8];
            #pragma unroll
            for (int jj = 0; jj < 6; jj++)
                #pragma unroll
                for (int tt = 0; tt < 2; tt++)
                    qacc[jj][tt] = __builtin_amdgcn_mfma_f32_16x16x32_bf16(
                        af[jj], bfr[tt], qacc[jj][tt], 0, 0, 0);
        }
        #pragma unroll
        for (int jj = 0; jj < 6; jj++) {
            int jbase = wv * 96 + jj * 16 + lq * 4;
            #pragma unroll
            for (int tt = 0; tt < 2; tt++) {
                int tok = tt * 16 + lm;
                if (jbase < 128) {
                    float v0 = (qacc[jj][tt][0] + qkvbS[jbase+0]) * 0.17677669529663687f;
                    float v1 = (qacc[jj][tt][1] + qkvbS[jbase+1]) * 0.17677669529663687f;
                    float v2 = (qacc[jj][tt][2] + qkvbS[jbase+2]) * 0.17677669529663687f;
                    float v3 = (qacc[jj][tt][3] + qkvbS[jbase+3]) * 0.17677669529663687f;
                    unsigned p0 = (unsigned short)f2bf(v0) | ((unsigned)(unsigned short)f2bf(v1) << 16);
                    unsigned p1 = (unsigned short)f2bf(v2) | ((unsigned)(unsigned short)f2bf(v3) << 16);
                    *(unsigned*)&qkvs[tok * 264 + jbase]     = p0;
                    *(unsigned*)&qkvs[tok * 264 + jbase + 2] = p1;
                } else if (jbase < 256) {
                    float v0 = qacc[jj][tt][0] + qkvbS[jbase+0];
                    float v1 = qacc[jj][tt][1] + qkvbS[jbase+1];
                    float v2 = qacc[jj][tt][2] + qkvbS[jbase+2];
                    float v3 = qacc[jj][tt][3] + qkvbS[jbase+3];
                    unsigned p0 = (unsigned short)f2bf(v0) | ((unsigned)(unsigned short)f2bf(v1) << 16);
                    unsigned p1 = (unsigned short)f2bf(v2) | ((unsigned)(unsigned short)f2bf(v3) << 16);
                    *(unsigned*)&qkvs[tok * 264 + jbase]     = p0;
                    *(unsigned*)&qkvs[tok * 264 + jbase + 2] = p1;
                } else {
                    #pragma unroll
                    for (int r = 0; r < 4; r++) {
                        int d = jbase - 256 + r;
                        Vt[(tt * 128 + d) * 16 + lm] = f2bf(qacc[jj][tt][r] + qkvbS[jbase + r]);
                    }
                }
            }
        }
    }
    __syncthreads();

    // ---- Stage 4: scores + bias + mask + softmax (operand-swapped) ------
    {
        int w_ = wv >> 1;
        int hb = (wv & 1) * 2;
        int win = bid * 2 + w_;
        int wh = (win >> 6) & 63;
        int ww = win & 63;
        int nq = lm;                    // q token
        int r1 = nq >> 2, c1 = nq & 3;
        int reg1 = regionOf(wh * 4 + r1) * 3 + regionOf(ww * 4 + c1);
        #pragma unroll
        for (int hh = 0; hh < 2; hh++) {
            int h = hb + hh;
            short8 qa = *(const short8*)&qkvs[(w_ * 16 + lm) * 264 + h * 32 + lq * 8];
            short8 kb = *(const short8*)&qkvs[(w_ * 16 + lm) * 264 + 128 + h * 32 + lq * 8];
            f32x4 s = __builtin_amdgcn_mfma_f32_16x16x32_bf16(kb, qa, (f32x4)0.0f, 0, 0, 0);
            float v[4];
            #pragma unroll
            for (int r = 0; r < 4; r++) {
                int m = lq * 4 + r;
                int r2 = m >> 2, c2 = m & 3;
                int ridx = (r1 - r2 + 3) * 7 + (c1 - c2 + 3);
                v[r] = s[r] + rpbs[ridx * 4 + h];
                int reg2 = regionOf(wh * 4 + r2) * 3 + regionOf(ww * 4 + c2);
                if (reg2 != reg1) v[r] -= 100.f;
            }
            float mx = fmaxf(fmaxf(v[0], v[1]), fmaxf(v[2], v[3]));
            mx = fmaxf(mx, __shfl_xor(mx, 16));
            mx = fmaxf(mx, __shfl_xor(mx, 32));
            float e0 = __expf(v[0] - mx);
            float e1 = __expf(v[1] - mx);
            float e2 = __expf(v[2] - mx);
            float e3 = __expf(v[3] - mx);
            float ss = (e0 + e1) + (e2 + e3);
            ss += __shfl_xor(ss, 16);
            ss += __shfl_xor(ss, 32);
            float rinv = 1.0f / ss;
            unsigned plo = (unsigned short)f2bf(e0 * rinv) |
                           ((unsigned)(unsigned short)f2bf(e1 * rinv) << 16);
            unsigned phi = (unsigned short)f2bf(e2 * rinv) |
                           ((unsigned)(unsigned short)f2bf(e3 * rinv) << 16);
            unsigned long long pk = (unsigned long long)plo |
                                    ((unsigned long long)phi << 32);
            *(unsigned long long*)&Ps[((w_ * 4 + h) * 16 + lm) * 16 + lq * 4] = pk;
        }
    }
    __syncthreads();

    // ---- Stage 5: PV (zero-padded K=32 MFMA) ----------------------------
    {
        int w_ = wv >> 1;
        int hb = (wv & 1) * 2;
        #pragma unroll
        for (int hh = 0; hh < 2; hh++) {
            int h = hb + hh;
            #pragma unroll
            for (int dt = 0; dt < 2; dt++) {
                short8 pa = (short8)0;
                short8 vb = (short8)0;
                if (lq < 2) {
                    pa = *(const short8*)&Ps[((w_ * 4 + h) * 16 + lm) * 16 + lq * 8];
                    vb = *(const short8*)&Vt[(w_ * 128 + h * 32 + dt * 16 + lm) * 16 + lq * 8];
                }
                f32x4 o = __builtin_amdgcn_mfma_f32_16x16x32_bf16(pa, vb, (f32x4)0.0f, 0, 0, 0);
                #pragma unroll
                for (int r = 0; r < 4; r++) {
                    aoutS[(w_ * 16 + lq * 4 + r) * 136 + h * 32 + dt * 16 + lm] = f2bf(o[r]);
                }
            }
        }
    }
    __syncthreads();

    // ---- Stage 6: proj GEMM + shortcut ----------------------------------
    {
        f32x4 cacc[2][2];
        #pragma unroll
        for (int a = 0; a < 2; a++)
            #pragma unroll
            for (int t = 0; t < 2; t++) cacc[a][t] = (f32x4)0.0f;

        for (int ks = 0; ks < 4; ks++) {
            short8 af[2];
            #pragma unroll
            for (int jj = 0; jj < 2; jj++) {
                const int4v* gp = (const int4v*)(projw_rep +
                    (size_t)(wv * 32 + jj * 16 + lm) * 128 + ks * 32 + lq * 8);
                af[jj] = __builtin_bit_cast(short8, *gp);
            }
            short8 bfr[2];
            #pragma unroll
            for (int tt = 0; tt < 2; tt++)
                bfr[tt] = *(const short8*)&aoutS[(tt * 16 + lm) * 136 + ks * 32 + lq * 8];
            #pragma unroll
            for (int jj = 0; jj < 2; jj++)
                #pragma unroll
                for (int tt = 0; tt < 2; tt++)
                    cacc[jj][tt] = __builtin_amdgcn_mfma_f32_16x16x32_bf16(
                        af[jj], bfr[tt], cacc[jj][tt], 0, 0, 0);
        }
        __syncthreads();
        #pragma unroll
        for (int jj = 0; jj < 2; jj++) {
            int jbase = wv * 32 + jj * 16 + lq * 4;
            #pragma unroll
            for (int tt = 0; tt < 2; tt++) {
                int tok = tt * 16 + lm;
                float v0 = cacc[jj][tt][0] + projbS[jbase+0] + bf2f(Xb[tok * 136 + jbase+0]);
                float v1 = cacc[jj][tt][1] + projbS[jbase+1] + bf2f(Xb[tok * 136 + jbase+1]);
                float v2 = cacc[jj][tt][2] + projbS[jbase+2] + bf2f(Xb[tok * 136 + jbase+2]);
                float v3 = cacc[jj][tt][3] + projbS[jbase+3] + bf2f(Xb[tok * 136 + jbase+3]);
                unsigned p0 = (unsigned short)f2bf(v0) | ((unsigned)(unsigned short)f2bf(v1) << 16);
                unsigned p1 = (unsigned short)f2bf(v2) | ((unsigned)(unsigned short)f2bf(v3) << 16);
                *(unsigned*)&aoutS[tok * 136 + jbase]     = p0;
                *(unsigned*)&aoutS[tok * 136 + jbase + 2] = p1;
            }
        }
    }
    __syncthreads();

    // ---- Stage 7: NHWC store (rolled channel slot, 8B-aligned) ----------
    {
        #pragma unroll
        for (int k = 0; k < 4; k++) {
            int idx = k * 256 + tid;
            int j  = idx & 127;
            int c  = (idx >> 7) & 3;
            int w_ = idx >> 9;
            int win = bid * 2 + w_;
            int b   = win >> 12;
            int wh  = (win >> 6) & 63;
            int ww  = win & 63;
            int gw  = (ww * 4 + c + SHIFT) & 255;
            int slot0 = (wh * 4 + SHIFT + 1) & 255;   // multiple of 4, contiguous r=0..3
            unsigned short s0 = (unsigned short)aoutS[(w_ * 16 + 0 + c) * 136 + j];
            unsigned short s1 = (unsigned short)aoutS[(w_ * 16 + 4 + c) * 136 + j];
            unsigned short s2 = (unsigned short)aoutS[(w_ * 16 + 8 + c) * 136 + j];
            unsigned short s3 = (unsigned short)aoutS[(w_ * 16 + 12 + c) * 136 + j];
            unsigned long long pk =
                (unsigned long long)s0 | ((unsigned long long)s1 << 16) |
                ((unsigned long long)s2 << 32) | ((unsigned long long)s3 << 48);
            size_t base = (((size_t)b * 256 + gw) * 128 + j) * 256 + slot0;
            *(unsigned long long*)(xatt + base) = pk;
        }
    }
}

// ---------------------------------------------------------------------------
// Weight repack for convs: fold BN scale, fp32 -> bf16, per-tap layout.
// ---------------------------------------------------------------------------
__global__ __launch_bounds__(256) void repack3(
    const float* __restrict__ w, const float* __restrict__ bias,
    const float* __restrict__ g_, const float* __restrict__ b_,
    const float* __restrict__ m_, const float* __restrict__ v_,
    __hip_bfloat16* __restrict__ wrep, float* __restrict__ cconst, int roll)
{
    int idx = blockIdx.x * 256 + threadIdx.x;       // < 589824
    int co = idx / 2304;
    int rem = idx - co * 2304;
    int ci = rem / 9;
    int tap = rem - ci * 9;
    float s = g_[co] * rsqrtf(v_[co] + 1e-5f);
    int ci_s = (ci + roll) & 255;
    size_t o = ((((size_t)(co >> 7) * 8 + (ci_s >> 5)) * 9 + tap) * 128 + (co & 127)) * 32 + (ci_s & 31);
    wrep[o] = __float2bfloat16(w[idx] * s);
    if (rem == 0) cconst[co] = bias[co] * s + (b_[co] - m_[co] * s);
}

__global__ __launch_bounds__(256) void repack1(
    const float* __restrict__ w, const float* __restrict__ bias,
    const float* __restrict__ g_, const float* __restrict__ b_,
    const float* __restrict__ m_, const float* __restrict__ v_,
    __hip_bfloat16* __restrict__ wrep, float* __restrict__ cconst)
{
    int idx = blockIdx.x * 256 + threadIdx.x;       // < 65536
    int co = idx >> 8, ci = idx & 255;
    float s = g_[co] * rsqrtf(v_[co] + 1e-5f);
    int ci_s = (ci + 1) & 255;                      // xatt is rolled by +1
    wrep[(((size_t)(co >> 7) * 8 + (ci_s >> 5)) * 128 + (co & 127)) * 32 + (ci_s & 31)] =
        __float2bfloat16(w[idx] * s);
    if (ci == 0) cconst[co] += bias[co] * s + (b_[co] - m_[co] * s);
}

// ---------------------------------------------------------------------------
// MFMA implicit-GEMM 3x3 conv, round-8: NO LDS, NO BARRIERS.
// B-operand fragments load DIRECTLY from global (L1/L2-resident NHWC rows;
// fragment layout in LDS was a verbatim copy of the global layout).  Removes
// 2 barriers/cb + 192 DS ops/cb + pre[] staging regs — the 2-barrier
// structure's ~46% no-issue stall (guide m169: staging L2-fit data is pure
// overhead).  h-halo: wave-uniform row skip (exact zero-pad).  w-halo:
// clamped address + per-lane mask (only lanes w=-1 / w=128 exist).
// Wave mapping unchanged (2co x 2w); XCD swizzle; grid 2048.
// Occupancy now VGPR-limited (~4 waves/SIMD) instead of LDS-limited.
// ---------------------------------------------------------------------------
template<int HAS_IDC, int OUT_BF16>
__global__ __launch_bounds__(256) void conv_mfma(
    const __hip_bfloat16* __restrict__ xin,   // NHWC (n,256,128,256)
    const __hip_bfloat16* __restrict__ xidc,  // NHWC or null
    const __hip_bfloat16* __restrict__ wrep,
    const __hip_bfloat16* __restrict__ wrepi,
    const float* __restrict__ cconst,
    void* __restrict__ outp)
{
    const int tid = threadIdx.x;
    const int l  = tid & 63;
    const int wv = tid >> 6;
    const int wave_co = (wv & 1) * 64;
    const int wave_w  = (wv >> 1) * 64;
    // XCD swizzle: 2048 blocks = 8 XCDs x 256 contiguous (g,h,n) chunks
    const int nb = ((blockIdx.x & 7) << 8) | (blockIdx.x >> 3);
    const int g = nb & 1;
    const int h = (nb >> 1) & 255;
    const int n = nb >> 9;
    const int lq = l >> 4;
    const int lm = l & 15;

    f32x4 acc[4][4];
    #pragma unroll
    for (int a = 0; a < 4; a++)
        #pragma unroll
        for (int b = 0; b < 4; b++) acc[a][b] = (f32x4)0.0f;

    // wave-uniform row bases + validity for the 3 conv rows
    const __hip_bfloat16* rowp[3];
    bool rowok[3];
    #pragma unroll
    for (int kh = 0; kh < 3; kh++) {
        int hh = h - 1 + kh;
        rowok[kh] = (0 <= hh && hh < 256);
        int hcl = min(max(hh, 0), 255);
        rowp[kh] = xin + (((size_t)(n * 256 + hcl) * 128) << 8);
    }
    const __hip_bfloat16* idcp = HAS_IDC
        ? (xidc + (((size_t)(n * 256 + h) * 128) << 8)) : (const __hip_bfloat16*)nullptr;

    #pragma unroll 1
    for (int cb = 0; cb < 8; cb++) {
        #pragma unroll
        for (int tap = 0; tap < 9; tap++) {
            const int kh = tap / 3;
            const int kw = tap - kh * 3;
            if (!rowok[kh]) continue;          // wave-uniform zero-pad skip
            const __hip_bfloat16* ap = wrep + (((size_t)(g * 8 + cb) * 9 + tap) << 12);
            short8 afr[4];
            #pragma unroll
            for (int cs = 0; cs < 4; cs++)
                afr[cs] = __builtin_bit_cast(short8,
                    *(const int4v*)(ap + (size_t)(wave_co + cs * 16 + lm) * 32 + lq * 8));
            const __hip_bfloat16* bp = rowp[kh] + cb * 32;
            #pragma unroll
            for (int ws = 0; ws < 4; ws++) {
                int we = wave_w + ws * 16 + lm + kw - 1;
                int wc = (kw == 0) ? max(we, 0) : ((kw == 2) ? min(we, 127) : we);
                int4v bv = *(const int4v*)(bp + wc * 256 + lq * 8);
                if (kw != 1) {
                    int m = (we == wc) ? -1 : 0;
                    int4v mv = {m, m, m, m};
                    bv &= mv;                   // zero the single OOB edge lane
                }
                short8 bfr = __builtin_bit_cast(short8, bv);
                #pragma unroll
                for (int cs = 0; cs < 4; cs++)
                    acc[cs][ws] = __builtin_amdgcn_mfma_f32_16x16x32_bf16(
                        afr[cs], bfr, acc[cs][ws], 0, 0, 0);
            }
        }
        if constexpr (HAS_IDC) {
            const __hip_bfloat16* ap = wrepi + (((size_t)(g * 8 + cb)) << 12);
            short8 afr[4];
            #pragma unroll
            for (int cs = 0; cs < 4; cs++)
                afr[cs] = __builtin_bit_cast(short8,
                    *(const int4v*)(ap + (size_t)(wave_co + cs * 16 + lm) * 32 + lq * 8));
            const __hip_bfloat16* bp = idcp + cb * 32;
            #pragma unroll
            for (int ws = 0; ws < 4; ws++) {
                short8 bfr = __builtin_bit_cast(short8,
                    *(const int4v*)(bp + (size_t)(wave_w + ws * 16 + lm) * 256 + lq * 8));
                #pragma unroll
                for (int cs = 0; cs < 4; cs++)
                    acc[cs][ws] = __builtin_amdgcn_mfma_f32_16x16x32_bf16(
                        afr[cs], bfr, acc[cs][ws], 0, 0, 0);
            }
        }
    }

    // ---- epilogue ---------------------------------------------------------
    #pragma unroll
    for (int cs = 0; cs < 4; cs++) {
        int co0 = g * 128 + wave_co + cs * 16 + lq * 4;
        float c0 = cconst[co0 + 0], c1 = cconst[co0 + 1];
        float c2 = cconst[co0 + 2], c3 = cconst[co0 + 3];
        #pragma unroll
        for (int ws = 0; ws < 4; ws++) {
            int w = wave_w + ws * 16 + lm;
            float v0 = fmaxf(acc[cs][ws][0] + c0, 0.f);
            float v1 = fmaxf(acc[cs][ws][1] + c1, 0.f);
            float v2 = fmaxf(acc[cs][ws][2] + c2, 0.f);
            float v3 = fmaxf(acc[cs][ws][3] + c3, 0.f);
            if (OUT_BF16) {
                // NHWC bf16: 4 consecutive co per lane -> one 8B store
                unsigned long long pk =
                    (unsigned long long)(unsigned short)f2bf(v0) |
                    ((unsigned long long)(unsigned short)f2bf(v1) << 16) |
                    ((unsigned long long)(unsigned short)f2bf(v2) << 32) |
                    ((unsigned long long)(unsigned short)f2bf(v3) << 48);
                size_t base = ((((size_t)n * 256 + h) * 128 + w) << 8) + co0;
                *(unsigned long long*)((__hip_bfloat16*)outp + base) = pk;
            } else {
                // NCHW fp32 final output: coalesced dword stores
                float* op = (float*)outp;
                op[(((size_t)n * 256 + co0 + 0) * 256 + h) * 128 + w] = v0;
                op[(((size_t)n * 256 + co0 + 1) * 256 + h) * 128 + w] = v1;
                op[(((size_t)n * 256 + co0 + 2) * 256 + h) * 128 + w] = v2;
                op[(((size_t)n * 256 + co0 + 3) * 256 + h) * 128 + w] = v3;
            }
        }
    }
}

// ---------------------------------------------------------------------------
extern "C" void kernel_launch(void* const* d_in, const int* in_sizes, int n_in,
                              void* d_out, int out_size, void* d_ws, size_t ws_size,
                              hipStream_t stream) {
    const float* x       = (const float*)d_in[0];
    const float* qkv_w   = (const float*)d_in[1];
    const float* qkv_b   = (const float*)d_in[2];
    const float* proj_w  = (const float*)d_in[3];
    const float* proj_b  = (const float*)d_in[4];
    const float* rpb     = (const float*)d_in[5];
    const float* conv1_w = (const float*)d_in[6];
    const float* conv1_b = (const float*)d_in[7];
    const float* bn1_g   = (const float*)d_in[8];
    const float* bn1_b   = (const float*)d_in[9];
    const float* bn1_m   = (const float*)d_in[10];
    const float* bn1_v   = (const float*)d_in[11];
    const float* conv2_w = (const float*)d_in[12];
    const float* conv2_b = (const float*)d_in[13];
    const float* bn2_g   = (const float*)d_in[14];
    const float* bn2_b   = (const float*)d_in[15];
    const float* bn2_m   = (const float*)d_in[16];
    const float* bn2_v   = (const float*)d_in[17];
    const float* idc_w   = (const float*)d_in[18];
    const float* idc_b   = (const float*)d_in[19];
    const float* bni_g   = (const float*)d_in[20];
    const float* bni_b   = (const float*)d_in[21];
    const float* bni_m   = (const float*)d_in[22];
    const float* bni_v   = (const float*)d_in[23];

    const size_t TE = (size_t)BATCH * 256 * 256 * 128;    // 33,554,432
    char* ws = (char*)d_ws;
    __hip_bfloat16* xatt  = (__hip_bfloat16*)(ws);
    __hip_bfloat16* y1    = (__hip_bfloat16*)(ws + TE * 2);
    __hip_bfloat16* wrep1 = (__hip_bfloat16*)(ws + TE * 4);
    __hip_bfloat16* wrep2 = (__hip_bfloat16*)(ws + TE * 4 + 1179648);
    __hip_bfloat16* wrepi = (__hip_bfloat16*)(ws + TE * 4 + 2359296);
    float*          c1    = (float*)(ws + TE * 4 + 2490368);
    float*          c2    = (float*)(ws + TE * 4 + 2491392);
    __hip_bfloat16* qkvw_rep = (__hip_bfloat16*)(ws + TE * 4 + 2492416);
    __hip_bfloat16* projw_rep= (__hip_bfloat16*)(ws + TE * 4 + 2590720);

    repack3<<<2304, 256, 0, stream>>>(conv1_w, conv1_b, bn1_g, bn1_b, bn1_m, bn1_v, wrep1, c1, 1);
    repack3<<<2304, 256, 0, stream>>>(conv2_w, conv2_b, bn2_g, bn2_b, bn2_m, bn2_v, wrep2, c2, 0);
    repack1<<<256, 256, 0, stream>>>(idc_w, idc_b, bni_g, bni_b, bni_m, bni_v, wrepi, c2);
    repack_attnw<<<256, 256, 0, stream>>>(qkv_w, proj_w, qkvw_rep, projw_rep);

    attn_kernel<<<8192, 256, 0, stream>>>(x, qkvw_rep, projw_rep, qkv_b, proj_b, rpb, xatt);

    conv_mfma<0, 1><<<2048, 256, 0, stream>>>(xatt, nullptr, wrep1, nullptr, c1, (void*)y1);
    conv_mfma<1, 0><<<2048, 256, 0, stream>>>(y1, xatt, wrep2, wrepi, c2, d_out);
}

// Round 9
// 816.152 us; speedup vs baseline: 1.4819x; 1.4819x over previous
//
#include <hip/hip_runtime.h>
#include <hip/hip_bf16.h>
#include <math.h>
#include <cstddef>

// Problem constants
#define BATCH 4
#define WDIM 256
#define CDIM 128
#define WS 4
#define SHIFT 3
#define HEADS 4
#define HD 32
#define NTOK 16

typedef __attribute__((ext_vector_type(8))) short short8;
typedef __attribute__((ext_vector_type(4))) int int4v;
typedef __attribute__((ext_vector_type(4))) float f32x4;

__device__ __forceinline__ int regionOf(int v) {
    return v < (WDIM - WS) ? 0 : (v < (WDIM - SHIFT) ? 1 : 2);
}

__device__ __forceinline__ short f2bf(float v) {
    __hip_bfloat16 h = __float2bfloat16(v);
    return __builtin_bit_cast(short, h);
}
__device__ __forceinline__ float bf2f(short s) {
    unsigned u = ((unsigned)(unsigned short)s) << 16;
    return __builtin_bit_cast(float, u);
}

// ---------------------------------------------------------------------------
// Repack attention weights: [c][j] fp32 -> [j][c] bf16 (MFMA A-operand order)
// ---------------------------------------------------------------------------
__global__ __launch_bounds__(256) void repack_attnw(
    const float* __restrict__ qkv_w,   // (128, 384)
    const float* __restrict__ proj_w,  // (128, 128)
    __hip_bfloat16* __restrict__ qkvw_rep,   // (384, 128)
    __hip_bfloat16* __restrict__ projw_rep)  // (128, 128)
{
    int idx = blockIdx.x * 256 + threadIdx.x;   // < 65536
    if (idx < 49152) {
        int j = idx >> 7, c = idx & 127;
        qkvw_rep[idx] = __float2bfloat16(qkv_w[c * 384 + j]);
    } else {
        int k = idx - 49152;
        int j = k >> 7, c = k & 127;
        projw_rep[k] = __float2bfloat16(proj_w[c * 128 + j]);
    }
}

// ---------------------------------------------------------------------------
// Kernel A: fused upsample + shifted-window MSA + residual, MFMA version.
// R4 structure (col-major xrow, operand-swapped softmax) + round-9 additions:
//  * XCD-aware block swizzle (8192 = 8 XCDs x 1024): consecutive windows
//    share the same 4 upsampled source gh rows -> same-XCD L2 hits.
//  * s_setprio(1) around the stage-3 MFMA cluster (T5; m191 +4-7% attn).
// ---------------------------------------------------------------------------
#define XROW_RS 2114   // row stride in floats; 2114 mod 32 = 2 (bank spread)

__global__ __launch_bounds__(256, 4) void attn_kernel(
    const float* __restrict__ xin,
    const __hip_bfloat16* __restrict__ qkvw_rep,
    const __hip_bfloat16* __restrict__ projw_rep,
    const float* __restrict__ qkv_b,
    const float* __restrict__ proj_b,
    const float* __restrict__ rpb,
    __hip_bfloat16* __restrict__ xatt)
{
    __shared__ __align__(16) char smem[40864];
    float* xrowF  = (float*)smem;                      // col-major [2][64][33(n)]
    short* qkvs   = (short*)smem;                      // [32][264]
    short* aoutS  = (short*)smem;                      // [32][136]
    short* Xb     = (short*)(smem + 16912);            // [32][136]
    short* Ps     = (short*)(smem + 25616);            // [128][16]
    short* Vt     = (short*)(smem + 29712);            // [256][16]
    float* rpbs   = (float*)(smem + 37904);
    float* qkvbS  = (float*)(smem + 38688);
    float* projbS = (float*)(smem + 40224);
    float* tokw2  = (float*)(smem + 40736);

    const int tid = threadIdx.x;
    // XCD swizzle: 8192 blocks = 8 XCDs x 1024 contiguous window-pair chunks
    const int bid = ((blockIdx.x & 7) << 10) | (blockIdx.x >> 3);
    const int l   = tid & 63;
    const int wv  = tid >> 6;
    const int lm  = l & 15;
    const int lq  = l >> 4;

    if (tid < 196) rpbs[tid] = rpb[tid];
    for (int i = tid; i < 384; i += 256) qkvbS[i] = qkv_b[i];
    if (tid < 128) projbS[tid] = proj_b[tid];

    // ---- Stage 1: load raw rows (2 per token), scatter column-major -----
    #pragma unroll
    for (int k = 0; k < 4; k++) {
        int id = tid + k * 256;
        int n   = id >> 5;
        int row = (id >> 4) & 1;
        int ll  = id & 15;
        int w_  = n >> 4, nn = n & 15;
        int win = bid * 2 + w_;
        int b   = win >> 12;
        int wh  = (win >> 6) & 63;
        int ww  = win & 63;
        int r = nn >> 2, c = nn & 3;
        int gh = (wh * 4 + r + SHIFT) & 255;
        int gw = (ww * 4 + c + SHIFT) & 255;
        float pos2 = gw * (127.0f / 255.0f);
        int lo2 = (int)floorf(pos2);
        int hi2 = min(lo2 + 1, 127);
        if (row == 0 && ll == 0) tokw2[n] = pos2 - (float)lo2;
        int src = row == 0 ? lo2 : hi2;
        const float4* rp = (const float4*)(xin + (((size_t)b * 256 + gh) * 128 + src) * 64);
        float4 v = rp[ll];
        float* bp = xrowF + row * XROW_RS + n + (4 * ll) * 33;
        bp[0]      = v.x;
        bp[33]     = v.y;
        bp[66]     = v.z;
        bp[99]     = v.w;
    }
    __syncthreads();

    // ---- Stage 2: interp along last axis -> Xb bf16 ---------------------
    {
        int n = tid >> 3;
        int jj = tid & 7;
        float w2 = tokw2[n];
        const float* x0 = xrowF + n;
        const float* x1 = x0 + XROW_RS;
        #pragma unroll
        for (int p = 0; p < 8; p++) {
            unsigned pk = 0;
            #pragma unroll
            for (int q = 0; q < 2; q++) {
                int cc = jj * 16 + p * 2 + q;
                float pos3 = cc * (63.0f / 127.0f);
                int lo3 = (int)floorf(pos3);
                float w3 = pos3 - (float)lo3;
                int o = lo3 * 33;
                float v0 = x0[o] * (1.f - w3) + x0[o + 33] * w3;
                float v1 = x1[o] * (1.f - w3) + x1[o + 33] * w3;
                float out = v0 * (1.f - w2) + v1 * w2;
                pk |= ((unsigned)(unsigned short)f2bf(out)) << (16 * q);
            }
            *(unsigned*)&Xb[n * 136 + jj * 16 + p * 2] = pk;
        }
    }
    __syncthreads();

    // ---- Stage 3: QKV GEMM (M=384 j, N=32 tok, K=128) -------------------
    {
        f32x4 qacc[6][2];
        #pragma unroll
        for (int a = 0; a < 6; a++)
            #pragma unroll
            for (int t = 0; t < 2; t++) qacc[a][t] = (f32x4)0.0f;

        for (int ks = 0; ks < 4; ks++) {
            short8 af[6];
            #pragma unroll
            for (int jj = 0; jj < 6; jj++) {
                const int4v* gp = (const int4v*)(qkvw_rep +
                    (size_t)(wv * 96 + jj * 16 + lm) * 128 + ks * 32 + lq * 8);
                af[jj] = __builtin_bit_cast(short8, *gp);
            }
            short8 bfr[2];
            #pragma unroll
            for (int tt = 0; tt < 2; tt++)
                bfr[tt] = *(const short8*)&Xb[(tt * 16 + lm) * 136 + ks * 32 + lq * 8];
            __builtin_amdgcn_s_setprio(1);
            #pragma unroll
            for (int jj = 0; jj < 6; jj++)
                #pragma unroll
                for (int tt = 0; tt < 2; tt++)
                    qacc[jj][tt] = __builtin_amdgcn_mfma_f32_16x16x32_bf16(
                        af[jj], bfr[tt], qacc[jj][tt], 0, 0, 0);
            __builtin_amdgcn_s_setprio(0);
        }
        #pragma unroll
        for (int jj = 0; jj < 6; jj++) {
            int jbase = wv * 96 + jj * 16 + lq * 4;
            #pragma unroll
            for (int tt = 0; tt < 2; tt++) {
                int tok = tt * 16 + lm;
                if (jbase < 128) {
                    float v0 = (qacc[jj][tt][0] + qkvbS[jbase+0]) * 0.17677669529663687f;
                    float v1 = (qacc[jj][tt][1] + qkvbS[jbase+1]) * 0.17677669529663687f;
                    float v2 = (qacc[jj][tt][2] + qkvbS[jbase+2]) * 0.17677669529663687f;
                    float v3 = (qacc[jj][tt][3] + qkvbS[jbase+3]) * 0.17677669529663687f;
                    unsigned p0 = (unsigned short)f2bf(v0) | ((unsigned)(unsigned short)f2bf(v1) << 16);
                    unsigned p1 = (unsigned short)f2bf(v2) | ((unsigned)(unsigned short)f2bf(v3) << 16);
                    *(unsigned*)&qkvs[tok * 264 + jbase]     = p0;
                    *(unsigned*)&qkvs[tok * 264 + jbase + 2] = p1;
                } else if (jbase < 256) {
                    float v0 = qacc[jj][tt][0] + qkvbS[jbase+0];
                    float v1 = qacc[jj][tt][1] + qkvbS[jbase+1];
                    float v2 = qacc[jj][tt][2] + qkvbS[jbase+2];
                    float v3 = qacc[jj][tt][3] + qkvbS[jbase+3];
                    unsigned p0 = (unsigned short)f2bf(v0) | ((unsigned)(unsigned short)f2bf(v1) << 16);
                    unsigned p1 = (unsigned short)f2bf(v2) | ((unsigned)(unsigned short)f2bf(v3) << 16);
                    *(unsigned*)&qkvs[tok * 264 + jbase]     = p0;
                    *(unsigned*)&qkvs[tok * 264 + jbase + 2] = p1;
                } else {
                    #pragma unroll
                    for (int r = 0; r < 4; r++) {
                        int d = jbase - 256 + r;
                        Vt[(tt * 128 + d) * 16 + lm] = f2bf(qacc[jj][tt][r] + qkvbS[jbase + r]);
                    }
                }
            }
        }
    }
    __syncthreads();

    // ---- Stage 4: scores + bias + mask + softmax (operand-swapped) ------
    {
        int w_ = wv >> 1;
        int hb = (wv & 1) * 2;
        int win = bid * 2 + w_;
        int wh = (win >> 6) & 63;
        int ww = win & 63;
        int nq = lm;                    // q token
        int r1 = nq >> 2, c1 = nq & 3;
        int reg1 = regionOf(wh * 4 + r1) * 3 + regionOf(ww * 4 + c1);
        #pragma unroll
        for (int hh = 0; hh < 2; hh++) {
            int h = hb + hh;
            short8 qa = *(const short8*)&qkvs[(w_ * 16 + lm) * 264 + h * 32 + lq * 8];
            short8 kb = *(const short8*)&qkvs[(w_ * 16 + lm) * 264 + 128 + h * 32 + lq * 8];
            f32x4 s = __builtin_amdgcn_mfma_f32_16x16x32_bf16(kb, qa, (f32x4)0.0f, 0, 0, 0);
            float v[4];
            #pragma unroll
            for (int r = 0; r < 4; r++) {
                int m = lq * 4 + r;
                int r2 = m >> 2, c2 = m & 3;
                int ridx = (r1 - r2 + 3) * 7 + (c1 - c2 + 3);
                v[r] = s[r] + rpbs[ridx * 4 + h];
                int reg2 = regionOf(wh * 4 + r2) * 3 + regionOf(ww * 4 + c2);
                if (reg2 != reg1) v[r] -= 100.f;
            }
            float mx = fmaxf(fmaxf(v[0], v[1]), fmaxf(v[2], v[3]));
            mx = fmaxf(mx, __shfl_xor(mx, 16));
            mx = fmaxf(mx, __shfl_xor(mx, 32));
            float e0 = __expf(v[0] - mx);
            float e1 = __expf(v[1] - mx);
            float e2 = __expf(v[2] - mx);
            float e3 = __expf(v[3] - mx);
            float ss = (e0 + e1) + (e2 + e3);
            ss += __shfl_xor(ss, 16);
            ss += __shfl_xor(ss, 32);
            float rinv = 1.0f / ss;
            unsigned plo = (unsigned short)f2bf(e0 * rinv) |
                           ((unsigned)(unsigned short)f2bf(e1 * rinv) << 16);
            unsigned phi = (unsigned short)f2bf(e2 * rinv) |
                           ((unsigned)(unsigned short)f2bf(e3 * rinv) << 16);
            unsigned long long pk = (unsigned long long)plo |
                                    ((unsigned long long)phi << 32);
            *(unsigned long long*)&Ps[((w_ * 4 + h) * 16 + lm) * 16 + lq * 4] = pk;
        }
    }
    __syncthreads();

    // ---- Stage 5: PV (zero-padded K=32 MFMA) ----------------------------
    {
        int w_ = wv >> 1;
        int hb = (wv & 1) * 2;
        #pragma unroll
        for (int hh = 0; hh < 2; hh++) {
            int h = hb + hh;
            #pragma unroll
            for (int dt = 0; dt < 2; dt++) {
                short8 pa = (short8)0;
                short8 vb = (short8)0;
                if (lq < 2) {
                    pa = *(const short8*)&Ps[((w_ * 4 + h) * 16 + lm) * 16 + lq * 8];
                    vb = *(const short8*)&Vt[(w_ * 128 + h * 32 + dt * 16 + lm) * 16 + lq * 8];
                }
                f32x4 o = __builtin_amdgcn_mfma_f32_16x16x32_bf16(pa, vb, (f32x4)0.0f, 0, 0, 0);
                #pragma unroll
                for (int r = 0; r < 4; r++) {
                    aoutS[(w_ * 16 + lq * 4 + r) * 136 + h * 32 + dt * 16 + lm] = f2bf(o[r]);
                }
            }
        }
    }
    __syncthreads();

    // ---- Stage 6: proj GEMM + shortcut ----------------------------------
    {
        f32x4 cacc[2][2];
        #pragma unroll
        for (int a = 0; a < 2; a++)
            #pragma unroll
            for (int t = 0; t < 2; t++) cacc[a][t] = (f32x4)0.0f;

        for (int ks = 0; ks < 4; ks++) {
            short8 af[2];
            #pragma unroll
            for (int jj = 0; jj < 2; jj++) {
                const int4v* gp = (const int4v*)(projw_rep +
                    (size_t)(wv * 32 + jj * 16 + lm) * 128 + ks * 32 + lq * 8);
                af[jj] = __builtin_bit_cast(short8, *gp);
            }
            short8 bfr[2];
            #pragma unroll
            for (int tt = 0; tt < 2; tt++)
                bfr[tt] = *(const short8*)&aoutS[(tt * 16 + lm) * 136 + ks * 32 + lq * 8];
            #pragma unroll
            for (int jj = 0; jj < 2; jj++)
                #pragma unroll
                for (int tt = 0; tt < 2; tt++)
                    cacc[jj][tt] = __builtin_amdgcn_mfma_f32_16x16x32_bf16(
                        af[jj], bfr[tt], cacc[jj][tt], 0, 0, 0);
        }
        __syncthreads();
        #pragma unroll
        for (int jj = 0; jj < 2; jj++) {
            int jbase = wv * 32 + jj * 16 + lq * 4;
            #pragma unroll
            for (int tt = 0; tt < 2; tt++) {
                int tok = tt * 16 + lm;
                float v0 = cacc[jj][tt][0] + projbS[jbase+0] + bf2f(Xb[tok * 136 + jbase+0]);
                float v1 = cacc[jj][tt][1] + projbS[jbase+1] + bf2f(Xb[tok * 136 + jbase+1]);
                float v2 = cacc[jj][tt][2] + projbS[jbase+2] + bf2f(Xb[tok * 136 + jbase+2]);
                float v3 = cacc[jj][tt][3] + projbS[jbase+3] + bf2f(Xb[tok * 136 + jbase+3]);
                unsigned p0 = (unsigned short)f2bf(v0) | ((unsigned)(unsigned short)f2bf(v1) << 16);
                unsigned p1 = (unsigned short)f2bf(v2) | ((unsigned)(unsigned short)f2bf(v3) << 16);
                *(unsigned*)&aoutS[tok * 136 + jbase]     = p0;
                *(unsigned*)&aoutS[tok * 136 + jbase + 2] = p1;
            }
        }
    }
    __syncthreads();

    // ---- Stage 7: NHWC store (rolled channel slot, 8B-aligned) ----------
    {
        #pragma unroll
        for (int k = 0; k < 4; k++) {
            int idx = k * 256 + tid;
            int j  = idx & 127;
            int c  = (idx >> 7) & 3;
            int w_ = idx >> 9;
            int win = bid * 2 + w_;
            int b   = win >> 12;
            int wh  = (win >> 6) & 63;
            int ww  = win & 63;
            int gw  = (ww * 4 + c + SHIFT) & 255;
            int slot0 = (wh * 4 + SHIFT + 1) & 255;   // multiple of 4, contiguous r=0..3
            unsigned short s0 = (unsigned short)aoutS[(w_ * 16 + 0 + c) * 136 + j];
            unsigned short s1 = (unsigned short)aoutS[(w_ * 16 + 4 + c) * 136 + j];
            unsigned short s2 = (unsigned short)aoutS[(w_ * 16 + 8 + c) * 136 + j];
            unsigned short s3 = (unsigned short)aoutS[(w_ * 16 + 12 + c) * 136 + j];
            unsigned long long pk =
                (unsigned long long)s0 | ((unsigned long long)s1 << 16) |
                ((unsigned long long)s2 << 32) | ((unsigned long long)s3 << 48);
            size_t base = (((size_t)b * 256 + gw) * 128 + j) * 256 + slot0;
            *(unsigned long long*)(xatt + base) = pk;
        }
    }
}

// ---------------------------------------------------------------------------
// Weight repack for convs: fold BN scale, fp32 -> bf16, per-tap layout.
// ---------------------------------------------------------------------------
__global__ __launch_bounds__(256) void repack3(
    const float* __restrict__ w, const float* __restrict__ bias,
    const float* __restrict__ g_, const float* __restrict__ b_,
    const float* __restrict__ m_, const float* __restrict__ v_,
    __hip_bfloat16* __restrict__ wrep, float* __restrict__ cconst, int roll)
{
    int idx = blockIdx.x * 256 + threadIdx.x;       // < 589824
    int co = idx / 2304;
    int rem = idx - co * 2304;
    int ci = rem / 9;
    int tap = rem - ci * 9;
    float s = g_[co] * rsqrtf(v_[co] + 1e-5f);
    int ci_s = (ci + roll) & 255;
    size_t o = ((((size_t)(co >> 7) * 8 + (ci_s >> 5)) * 9 + tap) * 128 + (co & 127)) * 32 + (ci_s & 31);
    wrep[o] = __float2bfloat16(w[idx] * s);
    if (rem == 0) cconst[co] = bias[co] * s + (b_[co] - m_[co] * s);
}

__global__ __launch_bounds__(256) void repack1(
    const float* __restrict__ w, const float* __restrict__ bias,
    const float* __restrict__ g_, const float* __restrict__ b_,
    const float* __restrict__ m_, const float* __restrict__ v_,
    __hip_bfloat16* __restrict__ wrep, float* __restrict__ cconst)
{
    int idx = blockIdx.x * 256 + threadIdx.x;       // < 65536
    int co = idx >> 8, ci = idx & 255;
    float s = g_[co] * rsqrtf(v_[co] + 1e-5f);
    int ci_s = (ci + 1) & 255;                      // xatt is rolled by +1
    wrep[(((size_t)(co >> 7) * 8 + (ci_s >> 5)) * 128 + (co & 127)) * 32 + (ci_s & 31)] =
        __float2bfloat16(w[idx] * s);
    if (ci == 0) cconst[co] += bias[co] * s + (b_[co] - m_[co] * s);
}

// ---------------------------------------------------------------------------
// MFMA implicit-GEMM 3x3 conv on NHWC input (+ optional fused 1x1 branch).
// Round-9: EXACT round-3 body — the proven best (214.8 µs, 84 VGPR, no
// spill, FETCH 82 MB).  R6 (2-row tile), R7 (disjoint-w waves), R8 (no-LDS)
// all regressed: LDS staging + 2co x 2w wave map + XCD swizzle is the
// optimum of this 2-barrier structure family (MfmaUtil ~34.5% ceiling).
// ---------------------------------------------------------------------------
template<int HAS_IDC, int OUT_BF16>
__global__ __launch_bounds__(256) void conv_mfma(
    const __hip_bfloat16* __restrict__ xin,   // NHWC (n,256,128,256)
    const __hip_bfloat16* __restrict__ xidc,  // NHWC or null
    const __hip_bfloat16* __restrict__ wrep,
    const __hip_bfloat16* __restrict__ wrepi,
    const float* __restrict__ cconst,
    void* __restrict__ outp)
{
    constexpr int NROWS = HAS_IDC ? 4 : 3;
    constexpr int NPER  = NROWS * 2;            // 16B chunks per thread per cb
    constexpr int NTAPS = HAS_IDC ? 10 : 9;
    __shared__ __align__(16) short xs[NROWS * 130 * 40];

    const int tid = threadIdx.x;
    const int l  = tid & 63;
    const int wv = tid >> 6;
    const int wave_co = (wv & 1) * 64;
    const int wave_w  = (wv >> 1) * 64;
    // XCD swizzle: 2048 blocks = 8 XCDs x 256 contiguous (g,h,n) chunks
    const int nb = ((blockIdx.x & 7) << 8) | (blockIdx.x >> 3);
    const int g = nb & 1;
    const int h = (nb >> 1) & 255;
    const int n = nb >> 9;
    const int lq = l >> 4;
    const int lm = l & 15;

    // zero w-halo slots (only conv rows 0..2 have halo reads)
    if (tid < 192) {
        int row = tid >> 6;
        int side = (tid >> 5) & 1;
        int ci = tid & 31;
        xs[(row * 130 + (side ? 129 : 0)) * 40 + ci] = 0;
    }

    f32x4 acc[4][4];
    #pragma unroll
    for (int a = 0; a < 4; a++)
        #pragma unroll
        for (int b = 0; b < 4; b++) acc[a][b] = (f32x4)0.0f;

    int4v pre[NPER];
    // prefetch cb=0
    #pragma unroll
    for (int t = 0; t < NPER; t++) {
        int idx = t * 256 + tid;
        int c8  = idx & 3;
        int w   = (idx >> 2) & 127;
        int row = idx >> 9;
        int4v v = {0, 0, 0, 0};
        if (row < 3) {
            int hh = h - 1 + row;
            if (0 <= hh && hh < 256)
                v = *(const int4v*)(xin + ((((size_t)n * 256 + hh) * 128 + w) << 8) + c8 * 8);
        } else {
            v = *(const int4v*)(xidc + ((((size_t)n * 256 + h) * 128 + w) << 8) + c8 * 8);
        }
        pre[t] = v;
    }

    #pragma unroll 1
    for (int cb = 0; cb < 8; cb++) {
        __syncthreads();
        #pragma unroll
        for (int t = 0; t < NPER; t++) {
            int idx = t * 256 + tid;
            int c8  = idx & 3;
            int w   = (idx >> 2) & 127;
            int row = idx >> 9;
            *(int4v*)&xs[(row * 130 + w + 1) * 40 + c8 * 8] = pre[t];
        }
        __syncthreads();
        if (cb < 7) {
            #pragma unroll
            for (int t = 0; t < NPER; t++) {
                int idx = t * 256 + tid;
                int c8  = idx & 3;
                int w   = (idx >> 2) & 127;
                int row = idx >> 9;
                int4v v = {0, 0, 0, 0};
                if (row < 3) {
                    int hh = h - 1 + row;
                    if (0 <= hh && hh < 256)
                        v = *(const int4v*)(xin + ((((size_t)n * 256 + hh) * 128 + w) << 8)
                                            + (cb + 1) * 32 + c8 * 8);
                } else {
                    v = *(const int4v*)(xidc + ((((size_t)n * 256 + h) * 128 + w) << 8)
                                        + (cb + 1) * 32 + c8 * 8);
                }
                pre[t] = v;
            }
        }

        #pragma unroll 1
        for (int tap = 0; tap < NTAPS; tap++) {
            const __hip_bfloat16* ap;
            const short* bs;
            if (tap < 9) {
                int kh = tap / 3;
                int kw = tap - kh * 3;
                ap = wrep + ((((size_t)(g * 8 + cb) * 9 + tap)) << 12);
                bs = xs + (kh * 130 + wave_w + kw) * 40;
            } else {
                ap = wrepi + (((size_t)(g * 8 + cb)) << 12);
                bs = xs + (3 * 130 + wave_w + 1) * 40;
            }
            short8 afr[4];
            #pragma unroll
            for (int cs = 0; cs < 4; cs++) {
                const int4v* p4 = (const int4v*)(ap + (size_t)(wave_co + cs * 16 + lm) * 32 + lq * 8);
                afr[cs] = __builtin_bit_cast(short8, *p4);
            }
            #pragma unroll
            for (int ws = 0; ws < 4; ws++) {
                short8 bfr = __builtin_bit_cast(short8,
                    *(const int4v*)&bs[(ws * 16 + lm) * 40 + lq * 8]);
                #pragma unroll
                for (int cs = 0; cs < 4; cs++) {
                    acc[cs][ws] = __builtin_amdgcn_mfma_f32_16x16x32_bf16(
                        afr[cs], bfr, acc[cs][ws], 0, 0, 0);
                }
            }
        }
    }

    // ---- epilogue ---------------------------------------------------------
    #pragma unroll
    for (int cs = 0; cs < 4; cs++) {
        int co0 = g * 128 + wave_co + cs * 16 + lq * 4;
        float c0 = cconst[co0 + 0], c1 = cconst[co0 + 1];
        float c2 = cconst[co0 + 2], c3 = cconst[co0 + 3];
        #pragma unroll
        for (int ws = 0; ws < 4; ws++) {
            int w = wave_w + ws * 16 + lm;
            float v0 = fmaxf(acc[cs][ws][0] + c0, 0.f);
            float v1 = fmaxf(acc[cs][ws][1] + c1, 0.f);
            float v2 = fmaxf(acc[cs][ws][2] + c2, 0.f);
            float v3 = fmaxf(acc[cs][ws][3] + c3, 0.f);
            if (OUT_BF16) {
                // NHWC bf16: 4 consecutive co per lane -> one 8B store
                unsigned long long pk =
                    (unsigned long long)(unsigned short)f2bf(v0) |
                    ((unsigned long long)(unsigned short)f2bf(v1) << 16) |
                    ((unsigned long long)(unsigned short)f2bf(v2) << 32) |
                    ((unsigned long long)(unsigned short)f2bf(v3) << 48);
                size_t base = ((((size_t)n * 256 + h) * 128 + w) << 8) + co0;
                *(unsigned long long*)((__hip_bfloat16*)outp + base) = pk;
            } else {
                // NCHW fp32 final output: coalesced dword stores
                float* op = (float*)outp;
                op[(((size_t)n * 256 + co0 + 0) * 256 + h) * 128 + w] = v0;
                op[(((size_t)n * 256 + co0 + 1) * 256 + h) * 128 + w] = v1;
                op[(((size_t)n * 256 + co0 + 2) * 256 + h) * 128 + w] = v2;
                op[(((size_t)n * 256 + co0 + 3) * 256 + h) * 128 + w] = v3;
            }
        }
    }
}

// ---------------------------------------------------------------------------
extern "C" void kernel_launch(void* const* d_in, const int* in_sizes, int n_in,
                              void* d_out, int out_size, void* d_ws, size_t ws_size,
                              hipStream_t stream) {
    const float* x       = (const float*)d_in[0];
    const float* qkv_w   = (const float*)d_in[1];
    const float* qkv_b   = (const float*)d_in[2];
    const float* proj_w  = (const float*)d_in[3];
    const float* proj_b  = (const float*)d_in[4];
    const float* rpb     = (const float*)d_in[5];
    const float* conv1_w = (const float*)d_in[6];
    const float* conv1_b = (const float*)d_in[7];
    const float* bn1_g   = (const float*)d_in[8];
    const float* bn1_b   = (const float*)d_in[9];
    const float* bn1_m   = (const float*)d_in[10];
    const float* bn1_v   = (const float*)d_in[11];
    const float* conv2_w = (const float*)d_in[12];
    const float* conv2_b = (const float*)d_in[13];
    const float* bn2_g   = (const float*)d_in[14];
    const float* bn2_b   = (const float*)d_in[15];
    const float* bn2_m   = (const float*)d_in[16];
    const float* bn2_v   = (const float*)d_in[17];
    const float* idc_w   = (const float*)d_in[18];
    const float* idc_b   = (const float*)d_in[19];
    const float* bni_g   = (const float*)d_in[20];
    const float* bni_b   = (const float*)d_in[21];
    const float* bni_m   = (const float*)d_in[22];
    const float* bni_v   = (const float*)d_in[23];

    const size_t TE = (size_t)BATCH * 256 * 256 * 128;    // 33,554,432
    char* ws = (char*)d_ws;
    __hip_bfloat16* xatt  = (__hip_bfloat16*)(ws);
    __hip_bfloat16* y1    = (__hip_bfloat16*)(ws + TE * 2);
    __hip_bfloat16* wrep1 = (__hip_bfloat16*)(ws + TE * 4);
    __hip_bfloat16* wrep2 = (__hip_bfloat16*)(ws + TE * 4 + 1179648);
    __hip_bfloat16* wrepi = (__hip_bfloat16*)(ws + TE * 4 + 2359296);
    float*          c1    = (float*)(ws + TE * 4 + 2490368);
    float*          c2    = (float*)(ws + TE * 4 + 2491392);
    __hip_bfloat16* qkvw_rep = (__hip_bfloat16*)(ws + TE * 4 + 2492416);
    __hip_bfloat16* projw_rep= (__hip_bfloat16*)(ws + TE * 4 + 2590720);

    repack3<<<2304, 256, 0, stream>>>(conv1_w, conv1_b, bn1_g, bn1_b, bn1_m, bn1_v, wrep1, c1, 1);
    repack3<<<2304, 256, 0, stream>>>(conv2_w, conv2_b, bn2_g, bn2_b, bn2_m, bn2_v, wrep2, c2, 0);
    repack1<<<256, 256, 0, stream>>>(idc_w, idc_b, bni_g, bni_b, bni_m, bni_v, wrepi, c2);
    repack_attnw<<<256, 256, 0, stream>>>(qkv_w, proj_w, qkvw_rep, projw_rep);

    attn_kernel<<<8192, 256, 0, stream>>>(x, qkvw_rep, projw_rep, qkv_b, proj_b, rpb, xatt);

    conv_mfma<0, 1><<<2048, 256, 0, stream>>>(xatt, nullptr, wrep1, nullptr, c1, (void*)y1);
    conv_mfma<1, 0><<<2048, 256, 0, stream>>>(y1, xatt, wrep2, wrepi, c2, d_out);
}

// Round 10
// 710.144 us; speedup vs baseline: 1.7031x; 1.1493x over previous
//
#include <hip/hip_runtime.h>
#include <hip/hip_bf16.h>
#include <math.h>
#include <cstddef>

// Problem constants
#define BATCH 4
#define WDIM 256
#define CDIM 128
#define WS 4
#define SHIFT 3
#define HEADS 4
#define HD 32
#define NTOK 16

typedef __attribute__((ext_vector_type(8))) short short8;
typedef __attribute__((ext_vector_type(4))) int int4v;
typedef __attribute__((ext_vector_type(4))) float f32x4;

__device__ __forceinline__ int regionOf(int v) {
    return v < (WDIM - WS) ? 0 : (v < (WDIM - SHIFT) ? 1 : 2);
}

__device__ __forceinline__ short f2bf(float v) {
    __hip_bfloat16 h = __float2bfloat16(v);
    return __builtin_bit_cast(short, h);
}
__device__ __forceinline__ float bf2f(short s) {
    unsigned u = ((unsigned)(unsigned short)s) << 16;
    return __builtin_bit_cast(float, u);
}

// ---------------------------------------------------------------------------
// Repack attention weights: [c][j] fp32 -> [j][c] bf16 (MFMA A-operand order)
// ---------------------------------------------------------------------------
__global__ __launch_bounds__(256) void repack_attnw(
    const float* __restrict__ qkv_w,   // (128, 384)
    const float* __restrict__ proj_w,  // (128, 128)
    __hip_bfloat16* __restrict__ qkvw_rep,   // (384, 128)
    __hip_bfloat16* __restrict__ projw_rep)  // (128, 128)
{
    int idx = blockIdx.x * 256 + threadIdx.x;   // < 65536
    if (idx < 49152) {
        int j = idx >> 7, c = idx & 127;
        qkvw_rep[idx] = __float2bfloat16(qkv_w[c * 384 + j]);
    } else {
        int k = idx - 49152;
        int j = k >> 7, c = k & 127;
        projw_rep[k] = __float2bfloat16(proj_w[c * 128 + j]);
    }
}

// ---------------------------------------------------------------------------
// Kernel A: fused upsample + shifted-window MSA + residual, MFMA version.
// R4 structure (col-major xrow, operand-swapped softmax) + stage-3 setprio.
// Round-10: attn XCD swizzle REVERTED — stage-7 writes only 8B per 512B
// (b,gw,j) row; full lines assemble in L2 only because the 64 wh-variant
// blocks (stride 32 in bid) land on the same XCD under default round-robin
// (32 mod 8 == 0).  The swizzle broke that chain: WRITE_SIZE 82->330 MB.
// ---------------------------------------------------------------------------
#define XROW_RS 2114   // row stride in floats; 2114 mod 32 = 2 (bank spread)

__global__ __launch_bounds__(256, 4) void attn_kernel(
    const float* __restrict__ xin,
    const __hip_bfloat16* __restrict__ qkvw_rep,
    const __hip_bfloat16* __restrict__ projw_rep,
    const float* __restrict__ qkv_b,
    const float* __restrict__ proj_b,
    const float* __restrict__ rpb,
    __hip_bfloat16* __restrict__ xatt)
{
    __shared__ __align__(16) char smem[40864];
    float* xrowF  = (float*)smem;                      // col-major [2][64][33(n)]
    short* qkvs   = (short*)smem;                      // [32][264]
    short* aoutS  = (short*)smem;                      // [32][136]
    short* Xb     = (short*)(smem + 16912);            // [32][136]
    short* Ps     = (short*)(smem + 25616);            // [128][16]
    short* Vt     = (short*)(smem + 29712);            // [256][16]
    float* rpbs   = (float*)(smem + 37904);
    float* qkvbS  = (float*)(smem + 38688);
    float* projbS = (float*)(smem + 40224);
    float* tokw2  = (float*)(smem + 40736);

    const int tid = threadIdx.x;
    const int bid = blockIdx.x;   // NO swizzle (see header comment)
    const int l   = tid & 63;
    const int wv  = tid >> 6;
    const int lm  = l & 15;
    const int lq  = l >> 4;

    if (tid < 196) rpbs[tid] = rpb[tid];
    for (int i = tid; i < 384; i += 256) qkvbS[i] = qkv_b[i];
    if (tid < 128) projbS[tid] = proj_b[tid];

    // ---- Stage 1: load raw rows (2 per token), scatter column-major -----
    #pragma unroll
    for (int k = 0; k < 4; k++) {
        int id = tid + k * 256;
        int n   = id >> 5;
        int row = (id >> 4) & 1;
        int ll  = id & 15;
        int w_  = n >> 4, nn = n & 15;
        int win = bid * 2 + w_;
        int b   = win >> 12;
        int wh  = (win >> 6) & 63;
        int ww  = win & 63;
        int r = nn >> 2, c = nn & 3;
        int gh = (wh * 4 + r + SHIFT) & 255;
        int gw = (ww * 4 + c + SHIFT) & 255;
        float pos2 = gw * (127.0f / 255.0f);
        int lo2 = (int)floorf(pos2);
        int hi2 = min(lo2 + 1, 127);
        if (row == 0 && ll == 0) tokw2[n] = pos2 - (float)lo2;
        int src = row == 0 ? lo2 : hi2;
        const float4* rp = (const float4*)(xin + (((size_t)b * 256 + gh) * 128 + src) * 64);
        float4 v = rp[ll];
        float* bp = xrowF + row * XROW_RS + n + (4 * ll) * 33;
        bp[0]      = v.x;
        bp[33]     = v.y;
        bp[66]     = v.z;
        bp[99]     = v.w;
    }
    __syncthreads();

    // ---- Stage 2: interp along last axis -> Xb bf16 ---------------------
    {
        int n = tid >> 3;
        int jj = tid & 7;
        float w2 = tokw2[n];
        const float* x0 = xrowF + n;
        const float* x1 = x0 + XROW_RS;
        #pragma unroll
        for (int p = 0; p < 8; p++) {
            unsigned pk = 0;
            #pragma unroll
            for (int q = 0; q < 2; q++) {
                int cc = jj * 16 + p * 2 + q;
                float pos3 = cc * (63.0f / 127.0f);
                int lo3 = (int)floorf(pos3);
                float w3 = pos3 - (float)lo3;
                int o = lo3 * 33;
                float v0 = x0[o] * (1.f - w3) + x0[o + 33] * w3;
                float v1 = x1[o] * (1.f - w3) + x1[o + 33] * w3;
                float out = v0 * (1.f - w2) + v1 * w2;
                pk |= ((unsigned)(unsigned short)f2bf(out)) << (16 * q);
            }
            *(unsigned*)&Xb[n * 136 + jj * 16 + p * 2] = pk;
        }
    }
    __syncthreads();

    // ---- Stage 3: QKV GEMM (M=384 j, N=32 tok, K=128) -------------------
    {
        f32x4 qacc[6][2];
        #pragma unroll
        for (int a = 0; a < 6; a++)
            #pragma unroll
            for (int t = 0; t < 2; t++) qacc[a][t] = (f32x4)0.0f;

        for (int ks = 0; ks < 4; ks++) {
            short8 af[6];
            #pragma unroll
            for (int jj = 0; jj < 6; jj++) {
                const int4v* gp = (const int4v*)(qkvw_rep +
                    (size_t)(wv * 96 + jj * 16 + lm) * 128 + ks * 32 + lq * 8);
                af[jj] = __builtin_bit_cast(short8, *gp);
            }
            short8 bfr[2];
            #pragma unroll
            for (int tt = 0; tt < 2; tt++)
                bfr[tt] = *(const short8*)&Xb[(tt * 16 + lm) * 136 + ks * 32 + lq * 8];
            __builtin_amdgcn_s_setprio(1);
            #pragma unroll
            for (int jj = 0; jj < 6; jj++)
                #pragma unroll
                for (int tt = 0; tt < 2; tt++)
                    qacc[jj][tt] = __builtin_amdgcn_mfma_f32_16x16x32_bf16(
                        af[jj], bfr[tt], qacc[jj][tt], 0, 0, 0);
            __builtin_amdgcn_s_setprio(0);
        }
        #pragma unroll
        for (int jj = 0; jj < 6; jj++) {
            int jbase = wv * 96 + jj * 16 + lq * 4;
            #pragma unroll
            for (int tt = 0; tt < 2; tt++) {
                int tok = tt * 16 + lm;
                if (jbase < 128) {
                    float v0 = (qacc[jj][tt][0] + qkvbS[jbase+0]) * 0.17677669529663687f;
                    float v1 = (qacc[jj][tt][1] + qkvbS[jbase+1]) * 0.17677669529663687f;
                    float v2 = (qacc[jj][tt][2] + qkvbS[jbase+2]) * 0.17677669529663687f;
                    float v3 = (qacc[jj][tt][3] + qkvbS[jbase+3]) * 0.17677669529663687f;
                    unsigned p0 = (unsigned short)f2bf(v0) | ((unsigned)(unsigned short)f2bf(v1) << 16);
                    unsigned p1 = (unsigned short)f2bf(v2) | ((unsigned)(unsigned short)f2bf(v3) << 16);
                    *(unsigned*)&qkvs[tok * 264 + jbase]     = p0;
                    *(unsigned*)&qkvs[tok * 264 + jbase + 2] = p1;
                } else if (jbase < 256) {
                    float v0 = qacc[jj][tt][0] + qkvbS[jbase+0];
                    float v1 = qacc[jj][tt][1] + qkvbS[jbase+1];
                    float v2 = qacc[jj][tt][2] + qkvbS[jbase+2];
                    float v3 = qacc[jj][tt][3] + qkvbS[jbase+3];
                    unsigned p0 = (unsigned short)f2bf(v0) | ((unsigned)(unsigned short)f2bf(v1) << 16);
                    unsigned p1 = (unsigned short)f2bf(v2) | ((unsigned)(unsigned short)f2bf(v3) << 16);
                    *(unsigned*)&qkvs[tok * 264 + jbase]     = p0;
                    *(unsigned*)&qkvs[tok * 264 + jbase + 2] = p1;
                } else {
                    #pragma unroll
                    for (int r = 0; r < 4; r++) {
                        int d = jbase - 256 + r;
                        Vt[(tt * 128 + d) * 16 + lm] = f2bf(qacc[jj][tt][r] + qkvbS[jbase + r]);
                    }
                }
            }
        }
    }
    __syncthreads();

    // ---- Stage 4: scores + bias + mask + softmax (operand-swapped) ------
    {
        int w_ = wv >> 1;
        int hb = (wv & 1) * 2;
        int win = bid * 2 + w_;
        int wh = (win >> 6) & 63;
        int ww = win & 63;
        int nq = lm;                    // q token
        int r1 = nq >> 2, c1 = nq & 3;
        int reg1 = regionOf(wh * 4 + r1) * 3 + regionOf(ww * 4 + c1);
        #pragma unroll
        for (int hh = 0; hh < 2; hh++) {
            int h = hb + hh;
            short8 qa = *(const short8*)&qkvs[(w_ * 16 + lm) * 264 + h * 32 + lq * 8];
            short8 kb = *(const short8*)&qkvs[(w_ * 16 + lm) * 264 + 128 + h * 32 + lq * 8];
            f32x4 s = __builtin_amdgcn_mfma_f32_16x16x32_bf16(kb, qa, (f32x4)0.0f, 0, 0, 0);
            float v[4];
            #pragma unroll
            for (int r = 0; r < 4; r++) {
                int m = lq * 4 + r;
                int r2 = m >> 2, c2 = m & 3;
                int ridx = (r1 - r2 + 3) * 7 + (c1 - c2 + 3);
                v[r] = s[r] + rpbs[ridx * 4 + h];
                int reg2 = regionOf(wh * 4 + r2) * 3 + regionOf(ww * 4 + c2);
                if (reg2 != reg1) v[r] -= 100.f;
            }
            float mx = fmaxf(fmaxf(v[0], v[1]), fmaxf(v[2], v[3]));
            mx = fmaxf(mx, __shfl_xor(mx, 16));
            mx = fmaxf(mx, __shfl_xor(mx, 32));
            float e0 = __expf(v[0] - mx);
            float e1 = __expf(v[1] - mx);
            float e2 = __expf(v[2] - mx);
            float e3 = __expf(v[3] - mx);
            float ss = (e0 + e1) + (e2 + e3);
            ss += __shfl_xor(ss, 16);
            ss += __shfl_xor(ss, 32);
            float rinv = 1.0f / ss;
            unsigned plo = (unsigned short)f2bf(e0 * rinv) |
                           ((unsigned)(unsigned short)f2bf(e1 * rinv) << 16);
            unsigned phi = (unsigned short)f2bf(e2 * rinv) |
                           ((unsigned)(unsigned short)f2bf(e3 * rinv) << 16);
            unsigned long long pk = (unsigned long long)plo |
                                    ((unsigned long long)phi << 32);
            *(unsigned long long*)&Ps[((w_ * 4 + h) * 16 + lm) * 16 + lq * 4] = pk;
        }
    }
    __syncthreads();

    // ---- Stage 5: PV (zero-padded K=32 MFMA) ----------------------------
    {
        int w_ = wv >> 1;
        int hb = (wv & 1) * 2;
        #pragma unroll
        for (int hh = 0; hh < 2; hh++) {
            int h = hb + hh;
            #pragma unroll
            for (int dt = 0; dt < 2; dt++) {
                short8 pa = (short8)0;
                short8 vb = (short8)0;
                if (lq < 2) {
                    pa = *(const short8*)&Ps[((w_ * 4 + h) * 16 + lm) * 16 + lq * 8];
                    vb = *(const short8*)&Vt[(w_ * 128 + h * 32 + dt * 16 + lm) * 16 + lq * 8];
                }
                f32x4 o = __builtin_amdgcn_mfma_f32_16x16x32_bf16(pa, vb, (f32x4)0.0f, 0, 0, 0);
                #pragma unroll
                for (int r = 0; r < 4; r++) {
                    aoutS[(w_ * 16 + lq * 4 + r) * 136 + h * 32 + dt * 16 + lm] = f2bf(o[r]);
                }
            }
        }
    }
    __syncthreads();

    // ---- Stage 6: proj GEMM + shortcut ----------------------------------
    {
        f32x4 cacc[2][2];
        #pragma unroll
        for (int a = 0; a < 2; a++)
            #pragma unroll
            for (int t = 0; t < 2; t++) cacc[a][t] = (f32x4)0.0f;

        for (int ks = 0; ks < 4; ks++) {
            short8 af[2];
            #pragma unroll
            for (int jj = 0; jj < 2; jj++) {
                const int4v* gp = (const int4v*)(projw_rep +
                    (size_t)(wv * 32 + jj * 16 + lm) * 128 + ks * 32 + lq * 8);
                af[jj] = __builtin_bit_cast(short8, *gp);
            }
            short8 bfr[2];
            #pragma unroll
            for (int tt = 0; tt < 2; tt++)
                bfr[tt] = *(const short8*)&aoutS[(tt * 16 + lm) * 136 + ks * 32 + lq * 8];
            #pragma unroll
            for (int jj = 0; jj < 2; jj++)
                #pragma unroll
                for (int tt = 0; tt < 2; tt++)
                    cacc[jj][tt] = __builtin_amdgcn_mfma_f32_16x16x32_bf16(
                        af[jj], bfr[tt], cacc[jj][tt], 0, 0, 0);
        }
        __syncthreads();
        #pragma unroll
        for (int jj = 0; jj < 2; jj++) {
            int jbase = wv * 32 + jj * 16 + lq * 4;
            #pragma unroll
            for (int tt = 0; tt < 2; tt++) {
                int tok = tt * 16 + lm;
                float v0 = cacc[jj][tt][0] + projbS[jbase+0] + bf2f(Xb[tok * 136 + jbase+0]);
                float v1 = cacc[jj][tt][1] + projbS[jbase+1] + bf2f(Xb[tok * 136 + jbase+1]);
                float v2 = cacc[jj][tt][2] + projbS[jbase+2] + bf2f(Xb[tok * 136 + jbase+2]);
                float v3 = cacc[jj][tt][3] + projbS[jbase+3] + bf2f(Xb[tok * 136 + jbase+3]);
                unsigned p0 = (unsigned short)f2bf(v0) | ((unsigned)(unsigned short)f2bf(v1) << 16);
                unsigned p1 = (unsigned short)f2bf(v2) | ((unsigned)(unsigned short)f2bf(v3) << 16);
                *(unsigned*)&aoutS[tok * 136 + jbase]     = p0;
                *(unsigned*)&aoutS[tok * 136 + jbase + 2] = p1;
            }
        }
    }
    __syncthreads();

    // ---- Stage 7: NHWC store (rolled channel slot, 8B-aligned) ----------
    {
        #pragma unroll
        for (int k = 0; k < 4; k++) {
            int idx = k * 256 + tid;
            int j  = idx & 127;
            int c  = (idx >> 7) & 3;
            int w_ = idx >> 9;
            int win = bid * 2 + w_;
            int b   = win >> 12;
            int wh  = (win >> 6) & 63;
            int ww  = win & 63;
            int gw  = (ww * 4 + c + SHIFT) & 255;
            int slot0 = (wh * 4 + SHIFT + 1) & 255;   // multiple of 4, contiguous r=0..3
            unsigned short s0 = (unsigned short)aoutS[(w_ * 16 + 0 + c) * 136 + j];
            unsigned short s1 = (unsigned short)aoutS[(w_ * 16 + 4 + c) * 136 + j];
            unsigned short s2 = (unsigned short)aoutS[(w_ * 16 + 8 + c) * 136 + j];
            unsigned short s3 = (unsigned short)aoutS[(w_ * 16 + 12 + c) * 136 + j];
            unsigned long long pk =
                (unsigned long long)s0 | ((unsigned long long)s1 << 16) |
                ((unsigned long long)s2 << 32) | ((unsigned long long)s3 << 48);
            size_t base = (((size_t)b * 256 + gw) * 128 + j) * 256 + slot0;
            *(unsigned long long*)(xatt + base) = pk;
        }
    }
}

// ---------------------------------------------------------------------------
// Weight repack for convs: fold BN scale, fp32 -> bf16, per-tap layout.
// ---------------------------------------------------------------------------
__global__ __launch_bounds__(256) void repack3(
    const float* __restrict__ w, const float* __restrict__ bias,
    const float* __restrict__ g_, const float* __restrict__ b_,
    const float* __restrict__ m_, const float* __restrict__ v_,
    __hip_bfloat16* __restrict__ wrep, float* __restrict__ cconst, int roll)
{
    int idx = blockIdx.x * 256 + threadIdx.x;       // < 589824
    int co = idx / 2304;
    int rem = idx - co * 2304;
    int ci = rem / 9;
    int tap = rem - ci * 9;
    float s = g_[co] * rsqrtf(v_[co] + 1e-5f);
    int ci_s = (ci + roll) & 255;
    size_t o = ((((size_t)(co >> 7) * 8 + (ci_s >> 5)) * 9 + tap) * 128 + (co & 127)) * 32 + (ci_s & 31);
    wrep[o] = __float2bfloat16(w[idx] * s);
    if (rem == 0) cconst[co] = bias[co] * s + (b_[co] - m_[co] * s);
}

__global__ __launch_bounds__(256) void repack1(
    const float* __restrict__ w, const float* __restrict__ bias,
    const float* __restrict__ g_, const float* __restrict__ b_,
    const float* __restrict__ m_, const float* __restrict__ v_,
    __hip_bfloat16* __restrict__ wrep, float* __restrict__ cconst)
{
    int idx = blockIdx.x * 256 + threadIdx.x;       // < 65536
    int co = idx >> 8, ci = idx & 255;
    float s = g_[co] * rsqrtf(v_[co] + 1e-5f);
    int ci_s = (ci + 1) & 255;                      // xatt is rolled by +1
    wrep[(((size_t)(co >> 7) * 8 + (ci_s >> 5)) * 128 + (co & 127)) * 32 + (ci_s & 31)] =
        __float2bfloat16(w[idx] * s);
    if (ci == 0) cconst[co] += bias[co] * s + (b_[co] - m_[co] * s);
}

// ---------------------------------------------------------------------------
// MFMA implicit-GEMM 3x3 conv on NHWC input (+ optional fused 1x1 branch).
// EXACT round-3 body — the proven best (214.8 µs, 84 VGPR, no spill,
// FETCH 82 MB).  R6 (2-row tile), R7 (disjoint-w waves), R8 (no-LDS) all
// regressed: LDS staging + 2co x 2w wave map + XCD swizzle is the optimum
// of this 2-barrier structure family (MfmaUtil ~34.5% ceiling).
// ---------------------------------------------------------------------------
template<int HAS_IDC, int OUT_BF16>
__global__ __launch_bounds__(256) void conv_mfma(
    const __hip_bfloat16* __restrict__ xin,   // NHWC (n,256,128,256)
    const __hip_bfloat16* __restrict__ xidc,  // NHWC or null
    const __hip_bfloat16* __restrict__ wrep,
    const __hip_bfloat16* __restrict__ wrepi,
    const float* __restrict__ cconst,
    void* __restrict__ outp)
{
    constexpr int NROWS = HAS_IDC ? 4 : 3;
    constexpr int NPER  = NROWS * 2;            // 16B chunks per thread per cb
    constexpr int NTAPS = HAS_IDC ? 10 : 9;
    __shared__ __align__(16) short xs[NROWS * 130 * 40];

    const int tid = threadIdx.x;
    const int l  = tid & 63;
    const int wv = tid >> 6;
    const int wave_co = (wv & 1) * 64;
    const int wave_w  = (wv >> 1) * 64;
    // XCD swizzle: 2048 blocks = 8 XCDs x 256 contiguous (g,h,n) chunks
    const int nb = ((blockIdx.x & 7) << 8) | (blockIdx.x >> 3);
    const int g = nb & 1;
    const int h = (nb >> 1) & 255;
    const int n = nb >> 9;
    const int lq = l >> 4;
    const int lm = l & 15;

    // zero w-halo slots (only conv rows 0..2 have halo reads)
    if (tid < 192) {
        int row = tid >> 6;
        int side = (tid >> 5) & 1;
        int ci = tid & 31;
        xs[(row * 130 + (side ? 129 : 0)) * 40 + ci] = 0;
    }

    f32x4 acc[4][4];
    #pragma unroll
    for (int a = 0; a < 4; a++)
        #pragma unroll
        for (int b = 0; b < 4; b++) acc[a][b] = (f32x4)0.0f;

    int4v pre[NPER];
    // prefetch cb=0
    #pragma unroll
    for (int t = 0; t < NPER; t++) {
        int idx = t * 256 + tid;
        int c8  = idx & 3;
        int w   = (idx >> 2) & 127;
        int row = idx >> 9;
        int4v v = {0, 0, 0, 0};
        if (row < 3) {
            int hh = h - 1 + row;
            if (0 <= hh && hh < 256)
                v = *(const int4v*)(xin + ((((size_t)n * 256 + hh) * 128 + w) << 8) + c8 * 8);
        } else {
            v = *(const int4v*)(xidc + ((((size_t)n * 256 + h) * 128 + w) << 8) + c8 * 8);
        }
        pre[t] = v;
    }

    #pragma unroll 1
    for (int cb = 0; cb < 8; cb++) {
        __syncthreads();
        #pragma unroll
        for (int t = 0; t < NPER; t++) {
            int idx = t * 256 + tid;
            int c8  = idx & 3;
            int w   = (idx >> 2) & 127;
            int row = idx >> 9;
            *(int4v*)&xs[(row * 130 + w + 1) * 40 + c8 * 8] = pre[t];
        }
        __syncthreads();
        if (cb < 7) {
            #pragma unroll
            for (int t = 0; t < NPER; t++) {
                int idx = t * 256 + tid;
                int c8  = idx & 3;
                int w   = (idx >> 2) & 127;
                int row = idx >> 9;
                int4v v = {0, 0, 0, 0};
                if (row < 3) {
                    int hh = h - 1 + row;
                    if (0 <= hh && hh < 256)
                        v = *(const int4v*)(xin + ((((size_t)n * 256 + hh) * 128 + w) << 8)
                                            + (cb + 1) * 32 + c8 * 8);
                } else {
                    v = *(const int4v*)(xidc + ((((size_t)n * 256 + h) * 128 + w) << 8)
                                        + (cb + 1) * 32 + c8 * 8);
                }
                pre[t] = v;
            }
        }

        #pragma unroll 1
        for (int tap = 0; tap < NTAPS; tap++) {
            const __hip_bfloat16* ap;
            const short* bs;
            if (tap < 9) {
                int kh = tap / 3;
                int kw = tap - kh * 3;
                ap = wrep + ((((size_t)(g * 8 + cb) * 9 + tap)) << 12);
                bs = xs + (kh * 130 + wave_w + kw) * 40;
            } else {
                ap = wrepi + (((size_t)(g * 8 + cb)) << 12);
                bs = xs + (3 * 130 + wave_w + 1) * 40;
            }
            short8 afr[4];
            #pragma unroll
            for (int cs = 0; cs < 4; cs++) {
                const int4v* p4 = (const int4v*)(ap + (size_t)(wave_co + cs * 16 + lm) * 32 + lq * 8);
                afr[cs] = __builtin_bit_cast(short8, *p4);
            }
            #pragma unroll
            for (int ws = 0; ws < 4; ws++) {
                short8 bfr = __builtin_bit_cast(short8,
                    *(const int4v*)&bs[(ws * 16 + lm) * 40 + lq * 8]);
                #pragma unroll
                for (int cs = 0; cs < 4; cs++) {
                    acc[cs][ws] = __builtin_amdgcn_mfma_f32_16x16x32_bf16(
                        afr[cs], bfr, acc[cs][ws], 0, 0, 0);
                }
            }
        }
    }

    // ---- epilogue ---------------------------------------------------------
    #pragma unroll
    for (int cs = 0; cs < 4; cs++) {
        int co0 = g * 128 + wave_co + cs * 16 + lq * 4;
        float c0 = cconst[co0 + 0], c1 = cconst[co0 + 1];
        float c2 = cconst[co0 + 2], c3 = cconst[co0 + 3];
        #pragma unroll
        for (int ws = 0; ws < 4; ws++) {
            int w = wave_w + ws * 16 + lm;
            float v0 = fmaxf(acc[cs][ws][0] + c0, 0.f);
            float v1 = fmaxf(acc[cs][ws][1] + c1, 0.f);
            float v2 = fmaxf(acc[cs][ws][2] + c2, 0.f);
            float v3 = fmaxf(acc[cs][ws][3] + c3, 0.f);
            if (OUT_BF16) {
                // NHWC bf16: 4 consecutive co per lane -> one 8B store
                unsigned long long pk =
                    (unsigned long long)(unsigned short)f2bf(v0) |
                    ((unsigned long long)(unsigned short)f2bf(v1) << 16) |
                    ((unsigned long long)(unsigned short)f2bf(v2) << 32) |
                    ((unsigned long long)(unsigned short)f2bf(v3) << 48);
                size_t base = ((((size_t)n * 256 + h) * 128 + w) << 8) + co0;
                *(unsigned long long*)((__hip_bfloat16*)outp + base) = pk;
            } else {
                // NCHW fp32 final output: coalesced dword stores
                float* op = (float*)outp;
                op[(((size_t)n * 256 + co0 + 0) * 256 + h) * 128 + w] = v0;
                op[(((size_t)n * 256 + co0 + 1) * 256 + h) * 128 + w] = v1;
                op[(((size_t)n * 256 + co0 + 2) * 256 + h) * 128 + w] = v2;
                op[(((size_t)n * 256 + co0 + 3) * 256 + h) * 128 + w] = v3;
            }
        }
    }
}

// ---------------------------------------------------------------------------
extern "C" void kernel_launch(void* const* d_in, const int* in_sizes, int n_in,
                              void* d_out, int out_size, void* d_ws, size_t ws_size,
                              hipStream_t stream) {
    const float* x       = (const float*)d_in[0];
    const float* qkv_w   = (const float*)d_in[1];
    const float* qkv_b   = (const float*)d_in[2];
    const float* proj_w  = (const float*)d_in[3];
    const float* proj_b  = (const float*)d_in[4];
    const float* rpb     = (const float*)d_in[5];
    const float* conv1_w = (const float*)d_in[6];
    const float* conv1_b = (const float*)d_in[7];
    const float* bn1_g   = (const float*)d_in[8];
    const float* bn1_b   = (const float*)d_in[9];
    const float* bn1_m   = (const float*)d_in[10];
    const float* bn1_v   = (const float*)d_in[11];
    const float* conv2_w = (const float*)d_in[12];
    const float* conv2_b = (const float*)d_in[13];
    const float* bn2_g   = (const float*)d_in[14];
    const float* bn2_b   = (const float*)d_in[15];
    const float* bn2_m   = (const float*)d_in[16];
    const float* bn2_v   = (const float*)d_in[17];
    const float* idc_w   = (const float*)d_in[18];
    const float* idc_b   = (const float*)d_in[19];
    const float* bni_g   = (const float*)d_in[20];
    const float* bni_b   = (const float*)d_in[21];
    const float* bni_m   = (const float*)d_in[22];
    const float* bni_v   = (const float*)d_in[23];

    const size_t TE = (size_t)BATCH * 256 * 256 * 128;    // 33,554,432
    char* ws = (char*)d_ws;
    __hip_bfloat16* xatt  = (__hip_bfloat16*)(ws);
    __hip_bfloat16* y1    = (__hip_bfloat16*)(ws + TE * 2);
    __hip_bfloat16* wrep1 = (__hip_bfloat16*)(ws + TE * 4);
    __hip_bfloat16* wrep2 = (__hip_bfloat16*)(ws + TE * 4 + 1179648);
    __hip_bfloat16* wrepi = (__hip_bfloat16*)(ws + TE * 4 + 2359296);
    float*          c1    = (float*)(ws + TE * 4 + 2490368);
    float*          c2    = (float*)(ws + TE * 4 + 2491392);
    __hip_bfloat16* qkvw_rep = (__hip_bfloat16*)(ws + TE * 4 + 2492416);
    __hip_bfloat16* projw_rep= (__hip_bfloat16*)(ws + TE * 4 + 2590720);

    repack3<<<2304, 256, 0, stream>>>(conv1_w, conv1_b, bn1_g, bn1_b, bn1_m, bn1_v, wrep1, c1, 1);
    repack3<<<2304, 256, 0, stream>>>(conv2_w, conv2_b, bn2_g, bn2_b, bn2_m, bn2_v, wrep2, c2, 0);
    repack1<<<256, 256, 0, stream>>>(idc_w, idc_b, bni_g, bni_b, bni_m, bni_v, wrepi, c2);
    repack_attnw<<<256, 256, 0, stream>>>(qkv_w, proj_w, qkvw_rep, projw_rep);

    attn_kernel<<<8192, 256, 0, stream>>>(x, qkvw_rep, projw_rep, qkv_b, proj_b, rpb, xatt);

    conv_mfma<0, 1><<<2048, 256, 0, stream>>>(xatt, nullptr, wrep1, nullptr, c1, (void*)y1);
    conv_mfma<1, 0><<<2048, 256, 0, stream>>>(y1, xatt, wrep2, wrepi, c2, d_out);
}

// Round 11
// 709.114 us; speedup vs baseline: 1.7056x; 1.0015x over previous
//
#include <hip/hip_runtime.h>
#include <hip/hip_bf16.h>
#include <math.h>
#include <cstddef>

// Problem constants
#define BATCH 4
#define WDIM 256
#define CDIM 128
#define WS 4
#define SHIFT 3
#define HEADS 4
#define HD 32
#define NTOK 16

typedef __attribute__((ext_vector_type(8))) short short8;
typedef __attribute__((ext_vector_type(4))) int int4v;
typedef __attribute__((ext_vector_type(4))) float f32x4;

__device__ __forceinline__ int regionOf(int v) {
    return v < (WDIM - WS) ? 0 : (v < (WDIM - SHIFT) ? 1 : 2);
}

__device__ __forceinline__ short f2bf(float v) {
    __hip_bfloat16 h = __float2bfloat16(v);
    return __builtin_bit_cast(short, h);
}
__device__ __forceinline__ float bf2f(short s) {
    unsigned u = ((unsigned)(unsigned short)s) << 16;
    return __builtin_bit_cast(float, u);
}

// ---------------------------------------------------------------------------
// Repack attention weights: [c][j] fp32 -> [j][c] bf16 (MFMA A-operand order)
// ---------------------------------------------------------------------------
__global__ __launch_bounds__(256) void repack_attnw(
    const float* __restrict__ qkv_w,   // (128, 384)
    const float* __restrict__ proj_w,  // (128, 128)
    __hip_bfloat16* __restrict__ qkvw_rep,   // (384, 128)
    __hip_bfloat16* __restrict__ projw_rep)  // (128, 128)
{
    int idx = blockIdx.x * 256 + threadIdx.x;   // < 65536
    if (idx < 49152) {
        int j = idx >> 7, c = idx & 127;
        qkvw_rep[idx] = __float2bfloat16(qkv_w[c * 384 + j]);
    } else {
        int k = idx - 49152;
        int j = k >> 7, c = k & 127;
        projw_rep[k] = __float2bfloat16(proj_w[c * 128 + j]);
    }
}

// ---------------------------------------------------------------------------
// Kernel A: fused upsample + shifted-window MSA + residual, MFMA version.
// R10 proven version: col-major xrow, operand-swapped softmax, stage-3
// setprio, NO XCD swizzle (stage-7 scatter-writes rely on default
// round-robin to assemble full lines in L2 — R9 lesson, WRITE 82->330 MB).
// ---------------------------------------------------------------------------
#define XROW_RS 2114   // row stride in floats; 2114 mod 32 = 2 (bank spread)

__global__ __launch_bounds__(256, 4) void attn_kernel(
    const float* __restrict__ xin,
    const __hip_bfloat16* __restrict__ qkvw_rep,
    const __hip_bfloat16* __restrict__ projw_rep,
    const float* __restrict__ qkv_b,
    const float* __restrict__ proj_b,
    const float* __restrict__ rpb,
    __hip_bfloat16* __restrict__ xatt)
{
    __shared__ __align__(16) char smem[40864];
    float* xrowF  = (float*)smem;                      // col-major [2][64][33(n)]
    short* qkvs   = (short*)smem;                      // [32][264]
    short* aoutS  = (short*)smem;                      // [32][136]
    short* Xb     = (short*)(smem + 16912);            // [32][136]
    short* Ps     = (short*)(smem + 25616);            // [128][16]
    short* Vt     = (short*)(smem + 29712);            // [256][16]
    float* rpbs   = (float*)(smem + 37904);
    float* qkvbS  = (float*)(smem + 38688);
    float* projbS = (float*)(smem + 40224);
    float* tokw2  = (float*)(smem + 40736);

    const int tid = threadIdx.x;
    const int bid = blockIdx.x;   // NO swizzle (see header comment)
    const int l   = tid & 63;
    const int wv  = tid >> 6;
    const int lm  = l & 15;
    const int lq  = l >> 4;

    if (tid < 196) rpbs[tid] = rpb[tid];
    for (int i = tid; i < 384; i += 256) qkvbS[i] = qkv_b[i];
    if (tid < 128) projbS[tid] = proj_b[tid];

    // ---- Stage 1: load raw rows (2 per token), scatter column-major -----
    #pragma unroll
    for (int k = 0; k < 4; k++) {
        int id = tid + k * 256;
        int n   = id >> 5;
        int row = (id >> 4) & 1;
        int ll  = id & 15;
        int w_  = n >> 4, nn = n & 15;
        int win = bid * 2 + w_;
        int b   = win >> 12;
        int wh  = (win >> 6) & 63;
        int ww  = win & 63;
        int r = nn >> 2, c = nn & 3;
        int gh = (wh * 4 + r + SHIFT) & 255;
        int gw = (ww * 4 + c + SHIFT) & 255;
        float pos2 = gw * (127.0f / 255.0f);
        int lo2 = (int)floorf(pos2);
        int hi2 = min(lo2 + 1, 127);
        if (row == 0 && ll == 0) tokw2[n] = pos2 - (float)lo2;
        int src = row == 0 ? lo2 : hi2;
        const float4* rp = (const float4*)(xin + (((size_t)b * 256 + gh) * 128 + src) * 64);
        float4 v = rp[ll];
        float* bp = xrowF + row * XROW_RS + n + (4 * ll) * 33;
        bp[0]      = v.x;
        bp[33]     = v.y;
        bp[66]     = v.z;
        bp[99]     = v.w;
    }
    __syncthreads();

    // ---- Stage 2: interp along last axis -> Xb bf16 ---------------------
    {
        int n = tid >> 3;
        int jj = tid & 7;
        float w2 = tokw2[n];
        const float* x0 = xrowF + n;
        const float* x1 = x0 + XROW_RS;
        #pragma unroll
        for (int p = 0; p < 8; p++) {
            unsigned pk = 0;
            #pragma unroll
            for (int q = 0; q < 2; q++) {
                int cc = jj * 16 + p * 2 + q;
                float pos3 = cc * (63.0f / 127.0f);
                int lo3 = (int)floorf(pos3);
                float w3 = pos3 - (float)lo3;
                int o = lo3 * 33;
                float v0 = x0[o] * (1.f - w3) + x0[o + 33] * w3;
                float v1 = x1[o] * (1.f - w3) + x1[o + 33] * w3;
                float out = v0 * (1.f - w2) + v1 * w2;
                pk |= ((unsigned)(unsigned short)f2bf(out)) << (16 * q);
            }
            *(unsigned*)&Xb[n * 136 + jj * 16 + p * 2] = pk;
        }
    }
    __syncthreads();

    // ---- Stage 3: QKV GEMM (M=384 j, N=32 tok, K=128) -------------------
    {
        f32x4 qacc[6][2];
        #pragma unroll
        for (int a = 0; a < 6; a++)
            #pragma unroll
            for (int t = 0; t < 2; t++) qacc[a][t] = (f32x4)0.0f;

        for (int ks = 0; ks < 4; ks++) {
            short8 af[6];
            #pragma unroll
            for (int jj = 0; jj < 6; jj++) {
                const int4v* gp = (const int4v*)(qkvw_rep +
                    (size_t)(wv * 96 + jj * 16 + lm) * 128 + ks * 32 + lq * 8);
                af[jj] = __builtin_bit_cast(short8, *gp);
            }
            short8 bfr[2];
            #pragma unroll
            for (int tt = 0; tt < 2; tt++)
                bfr[tt] = *(const short8*)&Xb[(tt * 16 + lm) * 136 + ks * 32 + lq * 8];
            __builtin_amdgcn_s_setprio(1);
            #pragma unroll
            for (int jj = 0; jj < 6; jj++)
                #pragma unroll
                for (int tt = 0; tt < 2; tt++)
                    qacc[jj][tt] = __builtin_amdgcn_mfma_f32_16x16x32_bf16(
                        af[jj], bfr[tt], qacc[jj][tt], 0, 0, 0);
            __builtin_amdgcn_s_setprio(0);
        }
        #pragma unroll
        for (int jj = 0; jj < 6; jj++) {
            int jbase = wv * 96 + jj * 16 + lq * 4;
            #pragma unroll
            for (int tt = 0; tt < 2; tt++) {
                int tok = tt * 16 + lm;
                if (jbase < 128) {
                    float v0 = (qacc[jj][tt][0] + qkvbS[jbase+0]) * 0.17677669529663687f;
                    float v1 = (qacc[jj][tt][1] + qkvbS[jbase+1]) * 0.17677669529663687f;
                    float v2 = (qacc[jj][tt][2] + qkvbS[jbase+2]) * 0.17677669529663687f;
                    float v3 = (qacc[jj][tt][3] + qkvbS[jbase+3]) * 0.17677669529663687f;
                    unsigned p0 = (unsigned short)f2bf(v0) | ((unsigned)(unsigned short)f2bf(v1) << 16);
                    unsigned p1 = (unsigned short)f2bf(v2) | ((unsigned)(unsigned short)f2bf(v3) << 16);
                    *(unsigned*)&qkvs[tok * 264 + jbase]     = p0;
                    *(unsigned*)&qkvs[tok * 264 + jbase + 2] = p1;
                } else if (jbase < 256) {
                    float v0 = qacc[jj][tt][0] + qkvbS[jbase+0];
                    float v1 = qacc[jj][tt][1] + qkvbS[jbase+1];
                    float v2 = qacc[jj][tt][2] + qkvbS[jbase+2];
                    float v3 = qacc[jj][tt][3] + qkvbS[jbase+3];
                    unsigned p0 = (unsigned short)f2bf(v0) | ((unsigned)(unsigned short)f2bf(v1) << 16);
                    unsigned p1 = (unsigned short)f2bf(v2) | ((unsigned)(unsigned short)f2bf(v3) << 16);
                    *(unsigned*)&qkvs[tok * 264 + jbase]     = p0;
                    *(unsigned*)&qkvs[tok * 264 + jbase + 2] = p1;
                } else {
                    #pragma unroll
                    for (int r = 0; r < 4; r++) {
                        int d = jbase - 256 + r;
                        Vt[(tt * 128 + d) * 16 + lm] = f2bf(qacc[jj][tt][r] + qkvbS[jbase + r]);
                    }
                }
            }
        }
    }
    __syncthreads();

    // ---- Stage 4: scores + bias + mask + softmax (operand-swapped) ------
    {
        int w_ = wv >> 1;
        int hb = (wv & 1) * 2;
        int win = bid * 2 + w_;
        int wh = (win >> 6) & 63;
        int ww = win & 63;
        int nq = lm;                    // q token
        int r1 = nq >> 2, c1 = nq & 3;
        int reg1 = regionOf(wh * 4 + r1) * 3 + regionOf(ww * 4 + c1);
        #pragma unroll
        for (int hh = 0; hh < 2; hh++) {
            int h = hb + hh;
            short8 qa = *(const short8*)&qkvs[(w_ * 16 + lm) * 264 + h * 32 + lq * 8];
            short8 kb = *(const short8*)&qkvs[(w_ * 16 + lm) * 264 + 128 + h * 32 + lq * 8];
            f32x4 s = __builtin_amdgcn_mfma_f32_16x16x32_bf16(kb, qa, (f32x4)0.0f, 0, 0, 0);
            float v[4];
            #pragma unroll
            for (int r = 0; r < 4; r++) {
                int m = lq * 4 + r;
                int r2 = m >> 2, c2 = m & 3;
                int ridx = (r1 - r2 + 3) * 7 + (c1 - c2 + 3);
                v[r] = s[r] + rpbs[ridx * 4 + h];
                int reg2 = regionOf(wh * 4 + r2) * 3 + regionOf(ww * 4 + c2);
                if (reg2 != reg1) v[r] -= 100.f;
            }
            float mx = fmaxf(fmaxf(v[0], v[1]), fmaxf(v[2], v[3]));
            mx = fmaxf(mx, __shfl_xor(mx, 16));
            mx = fmaxf(mx, __shfl_xor(mx, 32));
            float e0 = __expf(v[0] - mx);
            float e1 = __expf(v[1] - mx);
            float e2 = __expf(v[2] - mx);
            float e3 = __expf(v[3] - mx);
            float ss = (e0 + e1) + (e2 + e3);
            ss += __shfl_xor(ss, 16);
            ss += __shfl_xor(ss, 32);
            float rinv = 1.0f / ss;
            unsigned plo = (unsigned short)f2bf(e0 * rinv) |
                           ((unsigned)(unsigned short)f2bf(e1 * rinv) << 16);
            unsigned phi = (unsigned short)f2bf(e2 * rinv) |
                           ((unsigned)(unsigned short)f2bf(e3 * rinv) << 16);
            unsigned long long pk = (unsigned long long)plo |
                                    ((unsigned long long)phi << 32);
            *(unsigned long long*)&Ps[((w_ * 4 + h) * 16 + lm) * 16 + lq * 4] = pk;
        }
    }
    __syncthreads();

    // ---- Stage 5: PV (zero-padded K=32 MFMA) ----------------------------
    {
        int w_ = wv >> 1;
        int hb = (wv & 1) * 2;
        #pragma unroll
        for (int hh = 0; hh < 2; hh++) {
            int h = hb + hh;
            #pragma unroll
            for (int dt = 0; dt < 2; dt++) {
                short8 pa = (short8)0;
                short8 vb = (short8)0;
                if (lq < 2) {
                    pa = *(const short8*)&Ps[((w_ * 4 + h) * 16 + lm) * 16 + lq * 8];
                    vb = *(const short8*)&Vt[(w_ * 128 + h * 32 + dt * 16 + lm) * 16 + lq * 8];
                }
                f32x4 o = __builtin_amdgcn_mfma_f32_16x16x32_bf16(pa, vb, (f32x4)0.0f, 0, 0, 0);
                #pragma unroll
                for (int r = 0; r < 4; r++) {
                    aoutS[(w_ * 16 + lq * 4 + r) * 136 + h * 32 + dt * 16 + lm] = f2bf(o[r]);
                }
            }
        }
    }
    __syncthreads();

    // ---- Stage 6: proj GEMM + shortcut ----------------------------------
    {
        f32x4 cacc[2][2];
        #pragma unroll
        for (int a = 0; a < 2; a++)
            #pragma unroll
            for (int t = 0; t < 2; t++) cacc[a][t] = (f32x4)0.0f;

        for (int ks = 0; ks < 4; ks++) {
            short8 af[2];
            #pragma unroll
            for (int jj = 0; jj < 2; jj++) {
                const int4v* gp = (const int4v*)(projw_rep +
                    (size_t)(wv * 32 + jj * 16 + lm) * 128 + ks * 32 + lq * 8);
                af[jj] = __builtin_bit_cast(short8, *gp);
            }
            short8 bfr[2];
            #pragma unroll
            for (int tt = 0; tt < 2; tt++)
                bfr[tt] = *(const short8*)&aoutS[(tt * 16 + lm) * 136 + ks * 32 + lq * 8];
            #pragma unroll
            for (int jj = 0; jj < 2; jj++)
                #pragma unroll
                for (int tt = 0; tt < 2; tt++)
                    cacc[jj][tt] = __builtin_amdgcn_mfma_f32_16x16x32_bf16(
                        af[jj], bfr[tt], cacc[jj][tt], 0, 0, 0);
        }
        __syncthreads();
        #pragma unroll
        for (int jj = 0; jj < 2; jj++) {
            int jbase = wv * 32 + jj * 16 + lq * 4;
            #pragma unroll
            for (int tt = 0; tt < 2; tt++) {
                int tok = tt * 16 + lm;
                float v0 = cacc[jj][tt][0] + projbS[jbase+0] + bf2f(Xb[tok * 136 + jbase+0]);
                float v1 = cacc[jj][tt][1] + projbS[jbase+1] + bf2f(Xb[tok * 136 + jbase+1]);
                float v2 = cacc[jj][tt][2] + projbS[jbase+2] + bf2f(Xb[tok * 136 + jbase+2]);
                float v3 = cacc[jj][tt][3] + projbS[jbase+3] + bf2f(Xb[tok * 136 + jbase+3]);
                unsigned p0 = (unsigned short)f2bf(v0) | ((unsigned)(unsigned short)f2bf(v1) << 16);
                unsigned p1 = (unsigned short)f2bf(v2) | ((unsigned)(unsigned short)f2bf(v3) << 16);
                *(unsigned*)&aoutS[tok * 136 + jbase]     = p0;
                *(unsigned*)&aoutS[tok * 136 + jbase + 2] = p1;
            }
        }
    }
    __syncthreads();

    // ---- Stage 7: NHWC store (rolled channel slot, 8B-aligned) ----------
    {
        #pragma unroll
        for (int k = 0; k < 4; k++) {
            int idx = k * 256 + tid;
            int j  = idx & 127;
            int c  = (idx >> 7) & 3;
            int w_ = idx >> 9;
            int win = bid * 2 + w_;
            int b   = win >> 12;
            int wh  = (win >> 6) & 63;
            int ww  = win & 63;
            int gw  = (ww * 4 + c + SHIFT) & 255;
            int slot0 = (wh * 4 + SHIFT + 1) & 255;   // multiple of 4, contiguous r=0..3
            unsigned short s0 = (unsigned short)aoutS[(w_ * 16 + 0 + c) * 136 + j];
            unsigned short s1 = (unsigned short)aoutS[(w_ * 16 + 4 + c) * 136 + j];
            unsigned short s2 = (unsigned short)aoutS[(w_ * 16 + 8 + c) * 136 + j];
            unsigned short s3 = (unsigned short)aoutS[(w_ * 16 + 12 + c) * 136 + j];
            unsigned long long pk =
                (unsigned long long)s0 | ((unsigned long long)s1 << 16) |
                ((unsigned long long)s2 << 32) | ((unsigned long long)s3 << 48);
            size_t base = (((size_t)b * 256 + gw) * 128 + j) * 256 + slot0;
            *(unsigned long long*)(xatt + base) = pk;
        }
    }
}

// ---------------------------------------------------------------------------
// Weight repack for convs: fold BN scale, fp32 -> bf16, per-tap layout.
// ---------------------------------------------------------------------------
__global__ __launch_bounds__(256) void repack3(
    const float* __restrict__ w, const float* __restrict__ bias,
    const float* __restrict__ g_, const float* __restrict__ b_,
    const float* __restrict__ m_, const float* __restrict__ v_,
    __hip_bfloat16* __restrict__ wrep, float* __restrict__ cconst, int roll)
{
    int idx = blockIdx.x * 256 + threadIdx.x;       // < 589824
    int co = idx / 2304;
    int rem = idx - co * 2304;
    int ci = rem / 9;
    int tap = rem - ci * 9;
    float s = g_[co] * rsqrtf(v_[co] + 1e-5f);
    int ci_s = (ci + roll) & 255;
    size_t o = ((((size_t)(co >> 7) * 8 + (ci_s >> 5)) * 9 + tap) * 128 + (co & 127)) * 32 + (ci_s & 31);
    wrep[o] = __float2bfloat16(w[idx] * s);
    if (rem == 0) cconst[co] = bias[co] * s + (b_[co] - m_[co] * s);
}

__global__ __launch_bounds__(256) void repack1(
    const float* __restrict__ w, const float* __restrict__ bias,
    const float* __restrict__ g_, const float* __restrict__ b_,
    const float* __restrict__ m_, const float* __restrict__ v_,
    __hip_bfloat16* __restrict__ wrep, float* __restrict__ cconst)
{
    int idx = blockIdx.x * 256 + threadIdx.x;       // < 65536
    int co = idx >> 8, ci = idx & 255;
    float s = g_[co] * rsqrtf(v_[co] + 1e-5f);
    int ci_s = (ci + 1) & 255;                      // xatt is rolled by +1
    wrep[(((size_t)(co >> 7) * 8 + (ci_s >> 5)) * 128 + (co & 127)) * 32 + (ci_s & 31)] =
        __float2bfloat16(w[idx] * s);
    if (ci == 0) cconst[co] += bias[co] * s + (b_[co] - m_[co] * s);
}

// ---------------------------------------------------------------------------
// MFMA implicit-GEMM 3x3 conv — R3/R10 structure, round-11 change:
// LINEAR stride-32 LDS + XOR swizzle (T2) instead of stride-40 padding.
//   position(wslot, q) holds data(w, q ^ f(wslot)),  f(wslot)=(wslot>>1)&3
//   write: q = c8 ^ f;  read: q = lq ^ f  (involution, both sides)
// Bank math: read banks 16*(wslot&1) + 4*(lq^f) -> 8 distinct per 8 lm
// (2-way = free, m136); writes 2-way.  Same conflict-freedom as the pad,
// but LDS drops 25%: conv1 24,960 B -> 6 blocks/CU, conv2 33,280 B ->
// 4 blocks/CU (was 3 — LDS-limited).  Occupancy was the binding constraint
// of the 2-barrier structure; staging/waves/swizzle/grid all unchanged.
// ---------------------------------------------------------------------------
template<int HAS_IDC, int OUT_BF16>
__global__ __launch_bounds__(256) void conv_mfma(
    const __hip_bfloat16* __restrict__ xin,   // NHWC (n,256,128,256)
    const __hip_bfloat16* __restrict__ xidc,  // NHWC or null
    const __hip_bfloat16* __restrict__ wrep,
    const __hip_bfloat16* __restrict__ wrepi,
    const float* __restrict__ cconst,
    void* __restrict__ outp)
{
    constexpr int NROWS = HAS_IDC ? 4 : 3;
    constexpr int NPER  = NROWS * 2;            // 16B chunks per thread per cb
    constexpr int NTAPS = HAS_IDC ? 10 : 9;
    __shared__ __align__(16) short xs[NROWS * 130 * 32];

    const int tid = threadIdx.x;
    const int l  = tid & 63;
    const int wv = tid >> 6;
    const int wave_co = (wv & 1) * 64;
    const int wave_w  = (wv >> 1) * 64;
    // XCD swizzle: 2048 blocks = 8 XCDs x 256 contiguous (g,h,n) chunks
    const int nb = ((blockIdx.x & 7) << 8) | (blockIdx.x >> 3);
    const int g = nb & 1;
    const int h = (nb >> 1) & 255;
    const int n = nb >> 9;
    const int lq = l >> 4;
    const int lm = l & 15;

    // zero w-halo slots (wslot 0 and 129 of conv rows 0..2) — full 64B
    if (tid < 192) {
        int row = tid >> 6;
        int side = (tid >> 5) & 1;
        int ci = tid & 31;
        xs[(row * 130 + (side ? 129 : 0)) * 32 + ci] = 0;
    }

    f32x4 acc[4][4];
    #pragma unroll
    for (int a = 0; a < 4; a++)
        #pragma unroll
        for (int b = 0; b < 4; b++) acc[a][b] = (f32x4)0.0f;

    int4v pre[NPER];
    // prefetch cb=0
    #pragma unroll
    for (int t = 0; t < NPER; t++) {
        int idx = t * 256 + tid;
        int c8  = idx & 3;
        int w   = (idx >> 2) & 127;
        int row = idx >> 9;
        int4v v = {0, 0, 0, 0};
        if (row < 3) {
            int hh = h - 1 + row;
            if (0 <= hh && hh < 256)
                v = *(const int4v*)(xin + ((((size_t)n * 256 + hh) * 128 + w) << 8) + c8 * 8);
        } else {
            v = *(const int4v*)(xidc + ((((size_t)n * 256 + h) * 128 + w) << 8) + c8 * 8);
        }
        pre[t] = v;
    }

    #pragma unroll 1
    for (int cb = 0; cb < 8; cb++) {
        __syncthreads();
        #pragma unroll
        for (int t = 0; t < NPER; t++) {
            int idx = t * 256 + tid;
            int c8  = idx & 3;
            int w   = (idx >> 2) & 127;
            int row = idx >> 9;
            int wslot = w + 1;
            int q = c8 ^ ((wslot >> 1) & 3);      // T2 swizzle (write side)
            *(int4v*)&xs[(row * 130 + wslot) * 32 + q * 8] = pre[t];
        }
        __syncthreads();
        if (cb < 7) {
            #pragma unroll
            for (int t = 0; t < NPER; t++) {
                int idx = t * 256 + tid;
                int c8  = idx & 3;
                int w   = (idx >> 2) & 127;
                int row = idx >> 9;
                int4v v = {0, 0, 0, 0};
                if (row < 3) {
                    int hh = h - 1 + row;
                    if (0 <= hh && hh < 256)
                        v = *(const int4v*)(xin + ((((size_t)n * 256 + hh) * 128 + w) << 8)
                                            + (cb + 1) * 32 + c8 * 8);
                } else {
                    v = *(const int4v*)(xidc + ((((size_t)n * 256 + h) * 128 + w) << 8)
                                        + (cb + 1) * 32 + c8 * 8);
                }
                pre[t] = v;
            }
        }

        #pragma unroll 1
        for (int tap = 0; tap < NTAPS; tap++) {
            const __hip_bfloat16* ap;
            int kh_, kw_;
            if (tap < 9) {
                kh_ = tap / 3;
                kw_ = tap - kh_ * 3;
                ap = wrep + ((((size_t)(g * 8 + cb) * 9 + tap)) << 12);
            } else {
                kh_ = 3;
                kw_ = 1;
                ap = wrepi + (((size_t)(g * 8 + cb)) << 12);
            }
            short8 afr[4];
            #pragma unroll
            for (int cs = 0; cs < 4; cs++) {
                const int4v* p4 = (const int4v*)(ap + (size_t)(wave_co + cs * 16 + lm) * 32 + lq * 8);
                afr[cs] = __builtin_bit_cast(short8, *p4);
            }
            #pragma unroll
            for (int ws = 0; ws < 4; ws++) {
                int wslot = wave_w + ws * 16 + lm + kw_;
                int q = lq ^ ((wslot >> 1) & 3);  // T2 swizzle (read side)
                short8 bfr = __builtin_bit_cast(short8,
                    *(const int4v*)&xs[(kh_ * 130 + wslot) * 32 + q * 8]);
                #pragma unroll
                for (int cs = 0; cs < 4; cs++) {
                    acc[cs][ws] = __builtin_amdgcn_mfma_f32_16x16x32_bf16(
                        afr[cs], bfr, acc[cs][ws], 0, 0, 0);
                }
            }
        }
    }

    // ---- epilogue ---------------------------------------------------------
    #pragma unroll
    for (int cs = 0; cs < 4; cs++) {
        int co0 = g * 128 + wave_co + cs * 16 + lq * 4;
        float c0 = cconst[co0 + 0], c1 = cconst[co0 + 1];
        float c2 = cconst[co0 + 2], c3 = cconst[co0 + 3];
        #pragma unroll
        for (int ws = 0; ws < 4; ws++) {
            int w = wave_w + ws * 16 + lm;
            float v0 = fmaxf(acc[cs][ws][0] + c0, 0.f);
            float v1 = fmaxf(acc[cs][ws][1] + c1, 0.f);
            float v2 = fmaxf(acc[cs][ws][2] + c2, 0.f);
            float v3 = fmaxf(acc[cs][ws][3] + c3, 0.f);
            if (OUT_BF16) {
                // NHWC bf16: 4 consecutive co per lane -> one 8B store
                unsigned long long pk =
                    (unsigned long long)(unsigned short)f2bf(v0) |
                    ((unsigned long long)(unsigned short)f2bf(v1) << 16) |
                    ((unsigned long long)(unsigned short)f2bf(v2) << 32) |
                    ((unsigned long long)(unsigned short)f2bf(v3) << 48);
                size_t base = ((((size_t)n * 256 + h) * 128 + w) << 8) + co0;
                *(unsigned long long*)((__hip_bfloat16*)outp + base) = pk;
            } else {
                // NCHW fp32 final output: coalesced dword stores
                float* op = (float*)outp;
                op[(((size_t)n * 256 + co0 + 0) * 256 + h) * 128 + w] = v0;
                op[(((size_t)n * 256 + co0 + 1) * 256 + h) * 128 + w] = v1;
                op[(((size_t)n * 256 + co0 + 2) * 256 + h) * 128 + w] = v2;
                op[(((size_t)n * 256 + co0 + 3) * 256 + h) * 128 + w] = v3;
            }
        }
    }
}

// ---------------------------------------------------------------------------
extern "C" void kernel_launch(void* const* d_in, const int* in_sizes, int n_in,
                              void* d_out, int out_size, void* d_ws, size_t ws_size,
                              hipStream_t stream) {
    const float* x       = (const float*)d_in[0];
    const float* qkv_w   = (const float*)d_in[1];
    const float* qkv_b   = (const float*)d_in[2];
    const float* proj_w  = (const float*)d_in[3];
    const float* proj_b  = (const float*)d_in[4];
    const float* rpb     = (const float*)d_in[5];
    const float* conv1_w = (const float*)d_in[6];
    const float* conv1_b = (const float*)d_in[7];
    const float* bn1_g   = (const float*)d_in[8];
    const float* bn1_b   = (const float*)d_in[9];
    const float* bn1_m   = (const float*)d_in[10];
    const float* bn1_v   = (const float*)d_in[11];
    const float* conv2_w = (const float*)d_in[12];
    const float* conv2_b = (const float*)d_in[13];
    const float* bn2_g   = (const float*)d_in[14];
    const float* bn2_b   = (const float*)d_in[15];
    const float* bn2_m   = (const float*)d_in[16];
    const float* bn2_v   = (const float*)d_in[17];
    const float* idc_w   = (const float*)d_in[18];
    const float* idc_b   = (const float*)d_in[19];
    const float* bni_g   = (const float*)d_in[20];
    const float* bni_b   = (const float*)d_in[21];
    const float* bni_m   = (const float*)d_in[22];
    const float* bni_v   = (const float*)d_in[23];

    const size_t TE = (size_t)BATCH * 256 * 256 * 128;    // 33,554,432
    char* ws = (char*)d_ws;
    __hip_bfloat16* xatt  = (__hip_bfloat16*)(ws);
    __hip_bfloat16* y1    = (__hip_bfloat16*)(ws + TE * 2);
    __hip_bfloat16* wrep1 = (__hip_bfloat16*)(ws + TE * 4);
    __hip_bfloat16* wrep2 = (__hip_bfloat16*)(ws + TE * 4 + 1179648);
    __hip_bfloat16* wrepi = (__hip_bfloat16*)(ws + TE * 4 + 2359296);
    float*          c1    = (float*)(ws + TE * 4 + 2490368);
    float*          c2    = (float*)(ws + TE * 4 + 2491392);
    __hip_bfloat16* qkvw_rep = (__hip_bfloat16*)(ws + TE * 4 + 2492416);
    __hip_bfloat16* projw_rep= (__hip_bfloat16*)(ws + TE * 4 + 2590720);

    repack3<<<2304, 256, 0, stream>>>(conv1_w, conv1_b, bn1_g, bn1_b, bn1_m, bn1_v, wrep1, c1, 1);
    repack3<<<2304, 256, 0, stream>>>(conv2_w, conv2_b, bn2_g, bn2_b, bn2_m, bn2_v, wrep2, c2, 0);
    repack1<<<256, 256, 0, stream>>>(idc_w, idc_b, bni_g, bni_b, bni_m, bni_v, wrepi, c2);
    repack_attnw<<<256, 256, 0, stream>>>(qkv_w, proj_w, qkvw_rep, projw_rep);

    attn_kernel<<<8192, 256, 0, stream>>>(x, qkvw_rep, projw_rep, qkv_b, proj_b, rpb, xatt);

    conv_mfma<0, 1><<<2048, 256, 0, stream>>>(xatt, nullptr, wrep1, nullptr, c1, (void*)y1);
    conv_mfma<1, 0><<<2048, 256, 0, stream>>>(y1, xatt, wrep2, wrepi, c2, d_out);
}